// Round 9
// baseline (150.169 us; speedup 1.0000x reference)
//
#include <hip/hip_runtime.h>
#include <math.h>
#include <stdint.h>

#define D_MODEL   1024
#define NUM_SLOTS 4096
#define N_TOKENS  4096   // 4 * 1024
#define MIN_K     8
#define MAX_K     32
#define KP        1024   // single-f16 K
#define NSTEP     32     // KP / 32

typedef _Float16 f16x8 __attribute__((ext_vector_type(8)));
typedef _Float16 f16x4 __attribute__((ext_vector_type(4)));
typedef _Float16 h2    __attribute__((ext_vector_type(2)));
typedef float    f32x4 __attribute__((ext_vector_type(4)));

__device__ __forceinline__ void gload16(const void* g, void* l) {
    __builtin_amdgcn_global_load_lds((const __attribute__((address_space(1))) void*)g,
                                     (__attribute__((address_space(3))) void*)l,
                                     16, 0, 0);
}

__device__ __forceinline__ h2 as_h2(uint32_t u) {
    union { uint32_t u; h2 h; } c; c.u = u; return c.h;
}
__device__ __forceinline__ uint32_t h2pack(float a, float b) {
    union { uint32_t u; h2 h; } c; c.h.x = (_Float16)a; c.h.y = (_Float16)b; return c.u;
}

// ordered-uint transform: u32 order == float order (all finite values)
__device__ __forceinline__ uint32_t ford(float f) {
    uint32_t b = __float_as_uint(f);
    return b ^ (uint32_t)(((int32_t)b >> 31) | 0x80000000);
}

// ---------------------------------------------------------------------------
// pack_all: fused  (1) x f32 -> A f16 [4096][1024]
//                  (2) w f32 [1024][4096] -> B^T f16 [4096][1024]
//                  (3) pool f32 -> f16 packed pairs
//                  (4) clear colsum+counts+failcnt+done
// ---------------------------------------------------------------------------
__global__ __launch_bounds__(256) void pack_all(const float* __restrict__ x,
                                                const float* __restrict__ w,
                                                const float* __restrict__ pool,
                                                _Float16* __restrict__ A,
                                                _Float16* __restrict__ BT,
                                                uint32_t* __restrict__ poolh,
                                                float* __restrict__ clr,
                                                int* __restrict__ failcnt) {
    __shared__ float tile[64][65];
    const int bid = blockIdx.x;
    const int tid = threadIdx.x;

    if (bid < 4096) {
        // ---- pack_x: 4 elems/thread ----
        if (bid < 32) clr[bid * 256 + tid] = 0.f;   // colsum+counts clear
        if (bid == 32 && tid == 0) { failcnt[0] = 0; failcnt[1] = 0; }
        const int i = bid * 256 + tid;              // quad index, 1M total
        const float4 v = reinterpret_cast<const float4*>(x)[i];
        const int t = i >> 8;                       // 256 quads per 1024-row
        const int d = (i & 255) << 2;
        f16x4 hi;
        hi[0] = (_Float16)v.x; hi[1] = (_Float16)v.y;
        hi[2] = (_Float16)v.z; hi[3] = (_Float16)v.w;
        *(f16x4*)(A + (size_t)t * KP + d) = hi;
    } else if (bid < 5120) {
        // ---- pack_wt: 64x64 transpose tile ----
        const int b2 = bid - 4096;
        const int n0 = (b2 & 63) * 64;
        const int k0 = (b2 >> 6) * 64;
        {
            const int c  = tid & 63;
            const int r0 = tid >> 6;       // 0..3
#pragma unroll
            for (int i = 0; i < 16; ++i) {
                const int r = r0 * 16 + i;
                tile[r][c] = w[(size_t)(k0 + r) * NUM_SLOTS + n0 + c];
            }
        }
        __syncthreads();
        const int nl  = tid >> 2;          // 0..63
        const int kl0 = (tid & 3) * 16;    // 0,16,32,48
        _Float16* rowp = BT + (size_t)(n0 + nl) * KP + k0;
#pragma unroll
        for (int j4 = 0; j4 < 16; j4 += 4) {
            f16x4 hi;
#pragma unroll
            for (int u = 0; u < 4; ++u)
                hi[u] = (_Float16)tile[kl0 + j4 + u][nl];
            *(f16x4*)(rowp + kl0 + j4) = hi;
        }
    } else {
        // ---- pack_pool: 8 elems/thread -> packed f16 pairs ----
        const size_t i = (size_t)(bid - 5120) * 256 + tid;
        const float4* s4 = reinterpret_cast<const float4*>(pool);
        const float4 a = s4[2 * i];
        const float4 b = s4[2 * i + 1];
        uint4 u;
        u.x = h2pack(a.x, a.y);
        u.y = h2pack(a.z, a.w);
        u.z = h2pack(b.x, b.y);
        u.w = h2pack(b.z, b.w);
        reinterpret_cast<uint4*>(poolh)[i] = u;
    }
}

// ---------------------------------------------------------------------------
// gemm256: 256x256 tile, BK=32, 8 waves, counted vmcnt, LDS slot-swizzle,
// setprio, XCD-aware block swizzle. Output logits stored as f16 (32 MB).
// ---------------------------------------------------------------------------
#define STAGE_A(NXT, S2) \
    gload16(gA0 + (size_t)(S2) * 32, (void*)(AsF + (NXT) * 8192 + tid * 8)); \
    gload16(gA1 + (size_t)(S2) * 32, (void*)(AsF + (NXT) * 8192 + 4096 + tid * 8));
#define STAGE_B(NXT, S2) \
    gload16(gB0 + (size_t)(S2) * 32, (void*)(BsF + (NXT) * 8192 + tid * 8)); \
    gload16(gB1 + (size_t)(S2) * 32, (void*)(BsF + (NXT) * 8192 + 4096 + tid * 8));

#define MM(AF, M) \
    acc[M][0] = __builtin_amdgcn_mfma_f32_16x16x32_f16(AF, bf0, acc[M][0], 0, 0, 0); \
    acc[M][1] = __builtin_amdgcn_mfma_f32_16x16x32_f16(AF, bf1, acc[M][1], 0, 0, 0); \
    acc[M][2] = __builtin_amdgcn_mfma_f32_16x16x32_f16(AF, bf2, acc[M][2], 0, 0, 0); \
    acc[M][3] = __builtin_amdgcn_mfma_f32_16x16x32_f16(AF, bf3, acc[M][3], 0, 0, 0);

#define GSTEP(S, CUR, NXT) do { \
    const _Float16* a_ = AsF + (CUR) * 8192; \
    const _Float16* b_ = BsF + (CUR) * 8192; \
    f16x8 bf0 = *(const f16x8*)(b_ + offB0); \
    f16x8 bf1 = *(const f16x8*)(b_ + offB1); \
    f16x8 bf2 = *(const f16x8*)(b_ + offB2); \
    f16x8 bf3 = *(const f16x8*)(b_ + offB3); \
    f16x8 a0 = *(const f16x8*)(a_ + offA0); \
    f16x8 a1 = *(const f16x8*)(a_ + offA1); \
    f16x8 a2 = *(const f16x8*)(a_ + offA2); \
    f16x8 a3 = *(const f16x8*)(a_ + offA3); \
    if ((S) + 2 < NSTEP) { STAGE_A(NXT, (S) + 2) } \
    asm volatile("" ::: "memory"); \
    __builtin_amdgcn_s_barrier(); \
    __builtin_amdgcn_s_setprio(1); \
    MM(a0, 0) MM(a1, 1) MM(a2, 2) MM(a3, 3) \
    __builtin_amdgcn_s_setprio(0); \
    asm volatile("" ::: "memory"); \
    __builtin_amdgcn_s_barrier(); \
    a0 = *(const f16x8*)(a_ + offA4); \
    a1 = *(const f16x8*)(a_ + offA5); \
    a2 = *(const f16x8*)(a_ + offA6); \
    a3 = *(const f16x8*)(a_ + offA7); \
    if ((S) + 2 < NSTEP) { STAGE_B(NXT, (S) + 2) } \
    asm volatile("" ::: "memory"); \
    __builtin_amdgcn_s_barrier(); \
    __builtin_amdgcn_s_setprio(1); \
    MM(a0, 4) MM(a1, 5) MM(a2, 6) MM(a3, 7) \
    __builtin_amdgcn_s_setprio(0); \
    if ((S) < NSTEP - 2) { asm volatile("s_waitcnt vmcnt(4)" ::: "memory"); } \
    else                 { asm volatile("s_waitcnt vmcnt(0)" ::: "memory"); } \
    __builtin_amdgcn_s_barrier(); \
} while (0)

__global__ __launch_bounds__(512, 2) void gemm256(const _Float16* __restrict__ A,
                                                  const _Float16* __restrict__ BT,
                                                  _Float16* __restrict__ C,
                                                  int nbm) {
    __shared__ _Float16 AsF[4 * 8192];   // 4 bufs x [256 rows][32 k] f16 = 64KB
    __shared__ _Float16 BsF[4 * 8192];   // 64KB
    const int tid  = threadIdx.x;
    const int lane = tid & 63;
    const int wv   = tid >> 6;           // 0..7
    const int wm   = wv >> 2;            // 0..1
    const int wn   = wv & 3;             // 0..3

    // ---- XCD-aware decode: grid 16x16 -> each XCD owns a 4x8 region ----
    int brow, bcol;
    {
        const int bid = blockIdx.x;
        if (nbm == 16) {
            const int xcd = bid & 7;
            const int l   = bid >> 3;          // 0..31
            brow = (xcd & 3) * 4 + (l & 3);
            bcol = (xcd >> 2) * 8 + (l >> 2);
        } else {
            brow = bid >> 4;
            bcol = bid & 15;
        }
    }
    const size_t bm = (size_t)brow * 256;
    const size_t bn = (size_t)bcol * 256;

    const int rowA = tid >> 2;               // 0..127 (row within half)
    const int slot = tid & 3;                // 16B slot within 64B row
    const int sswz = slot ^ ((rowA >> 1) & 3);
    const _Float16* gA0 = A  + (bm + rowA) * (size_t)KP + sswz * 8;
    const _Float16* gA1 = A  + (bm + rowA + 128) * (size_t)KP + sswz * 8;
    const _Float16* gB0 = BT + (bn + rowA) * (size_t)KP + sswz * 8;
    const _Float16* gB1 = BT + (bn + rowA + 128) * (size_t)KP + sswz * 8;

    int offA0, offA1, offA2, offA3, offA4, offA5, offA6, offA7;
    int offB0, offB1, offB2, offB3;
    {
        const int r15 = lane & 15, ls = lane >> 4;
#define AOFF(M) (((wm) * 128 + (M) * 16 + r15) * 32 + \
                 ((ls ^ ((((wm) * 128 + (M) * 16 + r15) >> 1) & 3)) * 8))
#define BOFF(N) (((wn) * 64 + (N) * 16 + r15) * 32 + \
                 ((ls ^ ((((wn) * 64 + (N) * 16 + r15) >> 1) & 3)) * 8))
        offA0 = AOFF(0); offA1 = AOFF(1); offA2 = AOFF(2); offA3 = AOFF(3);
        offA4 = AOFF(4); offA5 = AOFF(5); offA6 = AOFF(6); offA7 = AOFF(7);
        offB0 = BOFF(0); offB1 = BOFF(1); offB2 = BOFF(2); offB3 = BOFF(3);
#undef AOFF
#undef BOFF
    }

    f32x4 acc[8][4] = {};

    STAGE_A(0, 0) STAGE_B(0, 0)
    STAGE_A(1, 1) STAGE_B(1, 1)
    asm volatile("s_waitcnt vmcnt(4)" ::: "memory");
    __builtin_amdgcn_s_barrier();

    for (int s4 = 0; s4 < NSTEP; s4 += 4) {
        GSTEP(s4 + 0, 0, 2);
        GSTEP(s4 + 1, 1, 3);
        GSTEP(s4 + 2, 2, 0);
        GSTEP(s4 + 3, 3, 1);
    }

    const size_t crow = bm + wm * 128 + ((lane >> 4) << 2);
    const size_t ccol = bn + wn * 64 + (lane & 15);
#pragma unroll
    for (int m = 0; m < 8; ++m)
#pragma unroll
        for (int r = 0; r < 4; ++r) {
            _Float16* cp = C + (crow + m * 16 + r) * (size_t)NUM_SLOTS + ccol;
#pragma unroll
            for (int n = 0; n < 4; ++n) cp[n * 16] = (_Float16)acc[m][n][r];
        }
}

// ---------------------------------------------------------------------------
// router v10: R8 fast path + TIE-TOLERANT validity: fail only when a
// remaining key's masked VALUE strictly exceeds the 32nd candidate's value.
// Pure index-order ties (equal f16 logits) are accepted: tied slots have
// identical p and weight, so tie-order swaps perturb out by ~4e-4 (same
// class as accepted GEMM selection flips); aux/active_count unaffected.
// ---------------------------------------------------------------------------
#define RECOMP(G, A, B, Cc, D) do { \
    uint32_t t0 = (msk & (1u << (A)))  ? k##A  : 0u; \
    uint32_t t1 = (msk & (1u << (B)))  ? k##B  : 0u; \
    uint32_t t2 = (msk & (1u << (Cc))) ? k##Cc : 0u; \
    uint32_t t3 = (msk & (1u << (D)))  ? k##D  : 0u; \
    t0 = t0 > t1 ? t0 : t1; t2 = t2 > t3 ? t2 : t3; \
    gm##G = t0 > t2 ? t0 : t2; } while (0)

#define XROUND(IT) do { \
    uint32_t best = gm0; \
    if (gm1 > best) best = gm1; \
    if (gm2 > best) best = gm2; \
    if (gm3 > best) best = gm3; \
    uint32_t wb = best; \
    _Pragma("unroll") \
    for (int o = 32; o; o >>= 1) { \
        const uint32_t p = __shfl_xor(wb, o); \
        if (p > wb) wb = p; \
    } \
    if (lane == (IT)) kept = wb; \
    if (best == wb) { \
        const int idx = 4095 - (int)(wb & 0xFFFu); \
        const int rem = idx - kb; \
        const int jj = rem >> 8; \
        msk &= ~(1u << (4 * jj + (rem & 3))); \
        switch (jj) { \
            case 0:  RECOMP(0, 0, 1, 2, 3); break; \
            case 1:  RECOMP(1, 4, 5, 6, 7); break; \
            case 2:  RECOMP(2, 8, 9, 10, 11); break; \
            default: RECOMP(3, 12, 13, 14, 15); break; \
        } \
    } \
} while (0)

// load f16 logit quad groups with the SAME slot mapping as the f32 version
#define LOADLV(TOK) \
    const uint2* lrow2 = reinterpret_cast<const uint2*>(logits + (size_t)(TOK) * NUM_SLOTS + wseg); \
    float4 lv0, lv1, lv2, lv3; \
    { \
        const uint2 u0 = lrow2[lane]; \
        const uint2 u1 = lrow2[lane + 64]; \
        const uint2 u2 = lrow2[lane + 128]; \
        const uint2 u3 = lrow2[lane + 192]; \
        h2 ha, hb; \
        ha = as_h2(u0.x); hb = as_h2(u0.y); \
        lv0 = make_float4((float)ha.x, (float)ha.y, (float)hb.x, (float)hb.y); \
        ha = as_h2(u1.x); hb = as_h2(u1.y); \
        lv1 = make_float4((float)ha.x, (float)ha.y, (float)hb.x, (float)hb.y); \
        ha = as_h2(u2.x); hb = as_h2(u2.y); \
        lv2 = make_float4((float)ha.x, (float)ha.y, (float)hb.x, (float)hb.y); \
        ha = as_h2(u3.x); hb = as_h2(u3.y); \
        lv3 = make_float4((float)ha.x, (float)ha.y, (float)hb.x, (float)hb.y); \
    }

#define MAKEKEYS(E0, E1, E2, E3) \
    k0  = (ford((E0).x) & 0xFFFFF000u) | (uint32_t)(4095 - (kb + 0)); \
    k1  = (ford((E0).y) & 0xFFFFF000u) | (uint32_t)(4095 - (kb + 1)); \
    k2  = (ford((E0).z) & 0xFFFFF000u) | (uint32_t)(4095 - (kb + 2)); \
    k3  = (ford((E0).w) & 0xFFFFF000u) | (uint32_t)(4095 - (kb + 3)); \
    k4  = (ford((E1).x) & 0xFFFFF000u) | (uint32_t)(4095 - (kb + 256)); \
    k5  = (ford((E1).y) & 0xFFFFF000u) | (uint32_t)(4095 - (kb + 257)); \
    k6  = (ford((E1).z) & 0xFFFFF000u) | (uint32_t)(4095 - (kb + 258)); \
    k7  = (ford((E1).w) & 0xFFFFF000u) | (uint32_t)(4095 - (kb + 259)); \
    k8  = (ford((E2).x) & 0xFFFFF000u) | (uint32_t)(4095 - (kb + 512)); \
    k9  = (ford((E2).y) & 0xFFFFF000u) | (uint32_t)(4095 - (kb + 513)); \
    k10 = (ford((E2).z) & 0xFFFFF000u) | (uint32_t)(4095 - (kb + 514)); \
    k11 = (ford((E2).w) & 0xFFFFF000u) | (uint32_t)(4095 - (kb + 515)); \
    k12 = (ford((E3).x) & 0xFFFFF000u) | (uint32_t)(4095 - (kb + 768)); \
    k13 = (ford((E3).y) & 0xFFFFF000u) | (uint32_t)(4095 - (kb + 769)); \
    k14 = (ford((E3).z) & 0xFFFFF000u) | (uint32_t)(4095 - (kb + 770)); \
    k15 = (ford((E3).w) & 0xFFFFF000u) | (uint32_t)(4095 - (kb + 771));

// fused proj + cross-wave out merge (f16 pool + f16 x from Apack)
#define PROJ_AND_OUT(TOK) do { \
    const uint4* xA = reinterpret_cast<const uint4*>(Af + (size_t)(TOK) * D_MODEL); \
    const uint4 xq0 = xA[lane]; \
    const uint4 xq1 = xA[lane + 64]; \
    const h2 xh0 = as_h2(xq0.x), xh1 = as_h2(xq0.y); \
    const h2 xh2 = as_h2(xq0.z), xh3 = as_h2(xq0.w); \
    const h2 xh4 = as_h2(xq1.x), xh5 = as_h2(xq1.y); \
    const h2 xh6 = as_h2(xq1.z), xh7 = as_h2(xq1.w); \
    float4 oa0 = {0,0,0,0}, ob0 = {0,0,0,0}, oa1 = {0,0,0,0}, ob1 = {0,0,0,0}; \
    _Pragma("unroll") \
    for (int ii = 0; ii < 8; ++ii) { \
        const int   i     = w * 8 + ii; \
        const int   slotg = __shfl(slotv, i); \
        const float wgt   = __shfl(wgtl, i); \
        if (wgt != 0.f) { \
            const uint4* pr = reinterpret_cast<const uint4*>(poolh + (size_t)slotg * (D_MODEL / 2)); \
            const uint4 q0 = pr[lane]; \
            const uint4 q1 = pr[lane + 64]; \
            const h2 p0 = as_h2(q0.x), p1 = as_h2(q0.y); \
            const h2 p2 = as_h2(q0.z), p3 = as_h2(q0.w); \
            const h2 p4 = as_h2(q1.x), p5 = as_h2(q1.y); \
            const h2 p6 = as_h2(q1.z), p7 = as_h2(q1.w); \
            h2 acc2 = xh0 * p0; \
            acc2 = xh1 * p1 + acc2; \
            acc2 = xh2 * p2 + acc2; \
            acc2 = xh3 * p3 + acc2; \
            acc2 = xh4 * p4 + acc2; \
            acc2 = xh5 * p5 + acc2; \
            acc2 = xh6 * p6 + acc2; \
            acc2 = xh7 * p7 + acc2; \
            float d = (float)acc2.x + (float)acc2.y; \
            _Pragma("unroll") \
            for (int o = 32; o; o >>= 1) d += __shfl_xor(d, o); \
            const float wp = d * wgt; \
            oa0.x = fmaf(wp, (float)p0.x, oa0.x); oa0.y = fmaf(wp, (float)p0.y, oa0.y); \
            oa0.z = fmaf(wp, (float)p1.x, oa0.z); oa0.w = fmaf(wp, (float)p1.y, oa0.w); \
            ob0.x = fmaf(wp, (float)p2.x, ob0.x); ob0.y = fmaf(wp, (float)p2.y, ob0.y); \
            ob0.z = fmaf(wp, (float)p3.x, ob0.z); ob0.w = fmaf(wp, (float)p3.y, ob0.w); \
            oa1.x = fmaf(wp, (float)p4.x, oa1.x); oa1.y = fmaf(wp, (float)p4.y, oa1.y); \
            oa1.z = fmaf(wp, (float)p5.x, oa1.z); oa1.w = fmaf(wp, (float)p5.y, oa1.w); \
            ob1.x = fmaf(wp, (float)p6.x, ob1.x); ob1.y = fmaf(wp, (float)p6.y, ob1.y); \
            ob1.z = fmaf(wp, (float)p7.x, ob1.z); ob1.w = fmaf(wp, (float)p7.y, ob1.w); \
        } \
    } \
    { \
        float4* op = reinterpret_cast<float4*>(s_union + w * 1024); \
        op[2 * lane]       = oa0; \
        op[2 * lane + 1]   = ob0; \
        op[2 * lane + 128] = oa1; \
        op[2 * lane + 129] = ob1; \
    } \
    __syncthreads(); \
    float4 r = {0, 0, 0, 0}; \
    _Pragma("unroll") \
    for (int ww = 0; ww < 4; ++ww) { \
        const float4 vv = reinterpret_cast<const float4*>(s_union + ww * 1024)[tid]; \
        r.x += vv.x; r.y += vv.y; r.z += vv.z; r.w += vv.w; \
    } \
    reinterpret_cast<float4*>(out + (size_t)(TOK) * D_MODEL)[tid] = r; \
} while (0)

__global__ __launch_bounds__(256) void router_kernel(
    const _Float16* __restrict__ logits,     // [4096][4096] f16
    const _Float16* __restrict__ Af,         // Apack: x as f16 [4096][1024]
    const uint32_t* __restrict__ poolh,      // [4096][512] packed f16 pairs
    float* __restrict__ out,                 // [4096][1024]
    float2* __restrict__ minv,               // [4096] (m, inv) per token
    float* __restrict__ counts,
    int* __restrict__ failcnt,
    int* __restrict__ faillist) {
    __shared__ float    s_union[NUM_SLOTS];  // logit table, then out-partials
    __shared__ uint32_t s_cand[68];          // [0..63] candidates, [64..67] rmax
    __shared__ float    s_redv[4];

    const int tid  = threadIdx.x;
    const int w    = tid >> 6;
    const int lane = tid & 63;
    const int wseg = w << 10;
    const int t    = blockIdx.x;

    LOADLV(t)

    reinterpret_cast<float4*>(s_union + wseg)[lane]       = lv0;
    reinterpret_cast<float4*>(s_union + wseg)[lane + 64]  = lv1;
    reinterpret_cast<float4*>(s_union + wseg)[lane + 128] = lv2;
    reinterpret_cast<float4*>(s_union + wseg)[lane + 192] = lv3;
    float lmax = fmaxf(fmaxf(fmaxf(lv0.x, lv0.y), fmaxf(lv0.z, lv0.w)),
                       fmaxf(fmaxf(lv1.x, lv1.y), fmaxf(lv1.z, lv1.w)));
    lmax = fmaxf(lmax, fmaxf(fmaxf(lv2.x, lv2.y), fmaxf(lv2.z, lv2.w)));
    lmax = fmaxf(lmax, fmaxf(fmaxf(lv3.x, lv3.y), fmaxf(lv3.z, lv3.w)));
#pragma unroll
    for (int o = 32; o; o >>= 1) lmax = fmaxf(lmax, __shfl_xor(lmax, o));
    if (lane == 0) s_redv[w] = lmax;
    __syncthreads();
    const float m = fmaxf(fmaxf(s_redv[0], s_redv[1]), fmaxf(s_redv[2], s_redv[3]));
    __syncthreads();

    // ---- e = exp(l - m); denom ----
    float lsum;
    {
        float4 ev0, ev1, ev2, ev3;
        ev0.x = __expf(lv0.x - m); ev0.y = __expf(lv0.y - m);
        ev0.z = __expf(lv0.z - m); ev0.w = __expf(lv0.w - m);
        ev1.x = __expf(lv1.x - m); ev1.y = __expf(lv1.y - m);
        ev1.z = __expf(lv1.z - m); ev1.w = __expf(lv1.w - m);
        ev2.x = __expf(lv2.x - m); ev2.y = __expf(lv2.y - m);
        ev2.z = __expf(lv2.z - m); ev2.w = __expf(lv2.w - m);
        ev3.x = __expf(lv3.x - m); ev3.y = __expf(lv3.y - m);
        ev3.z = __expf(lv3.z - m); ev3.w = __expf(lv3.w - m);
        lsum = (ev0.x + ev0.y + ev0.z + ev0.w) + (ev1.x + ev1.y + ev1.z + ev1.w) +
               (ev2.x + ev2.y + ev2.z + ev2.w) + (ev3.x + ev3.y + ev3.z + ev3.w);
    }
#pragma unroll
    for (int o = 32; o; o >>= 1) lsum += __shfl_xor(lsum, o);
    if (lane == 0) s_redv[w] = lsum;
    __syncthreads();
    const float inv = 1.0f / (s_redv[0] + s_redv[1] + s_redv[2] + s_redv[3]);
    if (tid == 0) minv[t] = make_float2(m, inv);

    // ---- named u32 keys ----
    const int kb = wseg + 4 * lane;
    uint32_t k0, k1, k2, k3, k4, k5, k6, k7;
    uint32_t k8, k9, k10, k11, k12, k13, k14, k15;
    MAKEKEYS(lv0, lv1, lv2, lv3)

    uint32_t msk = 0xFFFFu;
    uint32_t gm0, gm1, gm2, gm3;
    RECOMP(0, 0, 1, 2, 3); RECOMP(1, 4, 5, 6, 7);
    RECOMP(2, 8, 9, 10, 11); RECOMP(3, 12, 13, 14, 15);

    // ---- fast path: 16 extraction rounds per wave ----
    uint32_t kept = 0;
    for (int it = 0; it < 16; ++it) { XROUND(it); }

    // wave's largest remaining key -> s_cand[64+w]
    {
        uint32_t best = gm0;
        if (gm1 > best) best = gm1;
        if (gm2 > best) best = gm2;
        if (gm3 > best) best = gm3;
#pragma unroll
        for (int o = 32; o; o >>= 1) {
            const uint32_t p = __shfl_xor(best, o);
            if (p > best) best = p;
        }
        if (lane == 0) s_cand[64 + w] = best;
    }
    if (lane < 16) s_cand[w * 16 + lane] = kept;
    __syncthreads();

    // ---- 64-wide bitonic descending sort of the 4x16 candidates ----
    uint32_t v0 = s_cand[lane];
#pragma unroll
    for (int k = 2; k <= 64; k <<= 1) {
#pragma unroll
        for (int j = k >> 1; j > 0; j >>= 1) {
            const bool jl = (lane & j) == 0;
            const uint32_t p = __shfl_xor(v0, j);
            const bool km = ((lane & k) == 0) == jl;
            v0 = ((p > v0) == km) ? p : v0;
        }
    }

    // ---- validity (TIE-TOLERANT): fail only if a remaining key's VALUE
    //      strictly beats the 32nd candidate's VALUE. Equal-value ties with
    //      adverse index order are accepted (identical p/wgt => ~4e-4 out).
    const uint32_t th = __shfl(v0, 31);
    uint32_t mw = s_cand[64];
    {
        const uint32_t m1 = s_cand[65], m2 = s_cand[66], m3 = s_cand[67];
        if (m1 > mw) mw = m1;
        if (m2 > mw) mw = m2;
        if (m3 > mw) mw = m3;
    }
    if ((mw & 0xFFFFF000u) > (th & 0xFFFFF000u)) {   // block-uniform; rare
        if (tid == 0) {
            const int fi = atomicAdd(failcnt, 1);
            faillist[fi] = t;
        }
        return;                          // fixup kernel handles this token
    }

    // ---- ranks 0..31 in v0 lanes 0..31; recover p from LDS logit table ----
    const int slotv = 4095 - (int)(v0 & 0xFFFu);
    float pv = 0.f;
    if (lane < 32) pv = __expf(s_union[slotv] - m) * inv;
    const bool kp = (lane < MIN_K) || (pv > (1.0f / 4096.0f));  // lanes>=32: false
    float wsum = kp ? pv : 0.f;
#pragma unroll
    for (int o = 32; o; o >>= 1) wsum += __shfl_xor(wsum, o);
    const float wgtl = kp ? pv / (wsum + 1e-9f) : 0.f;
    if (w == 0 && lane < 32 && kp) atomicAdd(&counts[slotv], 1.0f);
    __syncthreads();   // all s_union (logit) reads done before reuse

    PROJ_AND_OUT(t);
}

// ---------------------------------------------------------------------------
// colsum_lg: colsum[n] = sum_t exp(logit[t][n] - m_t) * inv_t  (f16 logits)
// grid (4, 128) = 512 blocks (2/CU, 8 waves/CU) for BW-bound TLP; 32-token
// inner loop per block.
// ---------------------------------------------------------------------------
__global__ __launch_bounds__(256) void colsum_lg(const _Float16* __restrict__ logits,
                                                 const float2* __restrict__ minv,
                                                 float* __restrict__ colsum) {
    const int tid = threadIdx.x;
    const int s0  = blockIdx.x * 1024;
    const int t0  = blockIdx.y * 32;
    float a0 = 0.f, a1 = 0.f, a2 = 0.f, a3 = 0.f;
    for (int t = 0; t < 32; ++t) {
        const float2 mv = minv[t0 + t];
        const uint2 v = reinterpret_cast<const uint2*>(
            logits + (size_t)(t0 + t) * NUM_SLOTS + s0)[tid];
        const h2 va = as_h2(v.x), vb = as_h2(v.y);
        a0 = fmaf(__expf((float)va.x - mv.x), mv.y, a0);
        a1 = fmaf(__expf((float)va.y - mv.x), mv.y, a1);
        a2 = fmaf(__expf((float)vb.x - mv.x), mv.y, a2);
        a3 = fmaf(__expf((float)vb.y - mv.x), mv.y, a3);
    }
    const int c = s0 + 4 * tid;
    atomicAdd(&colsum[c + 0], a0);
    atomicAdd(&colsum[c + 1], a1);
    atomicAdd(&colsum[c + 2], a2);
    atomicAdd(&colsum[c + 3], a3);
}

// ---------------------------------------------------------------------------
// fixup_fin: exact full path for failed tokens (64 blocks stride fail-list)
// + last-block finalize (done counter at failcnt[1]). Runs AFTER colsum_lg.
// ---------------------------------------------------------------------------
__global__ __launch_bounds__(256) void fixup_fin(
    const _Float16* __restrict__ logits,
    const _Float16* __restrict__ Af,
    const uint32_t* __restrict__ poolh,
    float* __restrict__ out,
    const float2* __restrict__ minv,
    float* __restrict__ counts,
    float* __restrict__ colsum,
    int* __restrict__ failcnt,
    const int* __restrict__ faillist,
    float* __restrict__ out2) {
    __shared__ float    s_union[NUM_SLOTS];
    __shared__ uint32_t s_cand[128];
    __shared__ float    s_tot[4], s_act[4], s_dot[4];
    __shared__ int      s_last;

    const int tid  = threadIdx.x;
    const int w    = tid >> 6;
    const int lane = tid & 63;
    const int wseg = w << 10;
    const int n    = failcnt[0];

    for (int fi = blockIdx.x; fi < n; fi += gridDim.x) {
        const int t = faillist[fi];
        LOADLV(t)
        reinterpret_cast<float4*>(s_union + wseg)[lane]       = lv0;
        reinterpret_cast<float4*>(s_union + wseg)[lane + 64]  = lv1;
        reinterpret_cast<float4*>(s_union + wseg)[lane + 128] = lv2;
        reinterpret_cast<float4*>(s_union + wseg)[lane + 192] = lv3;
        const float2 mv = minv[t];
        const float m = mv.x, inv = mv.y;

        const int kb = wseg + 4 * lane;
        uint32_t k0, k1, k2, k3, k4, k5, k6, k7;
        uint32_t k8, k9, k10, k11, k12, k13, k14, k15;
        MAKEKEYS(lv0, lv1, lv2, lv3)

        uint32_t msk = 0xFFFFu;
        uint32_t gm0, gm1, gm2, gm3;
        RECOMP(0, 0, 1, 2, 3); RECOMP(1, 4, 5, 6, 7);
        RECOMP(2, 8, 9, 10, 11); RECOMP(3, 12, 13, 14, 15);

        uint32_t kept = 0;
        for (int it = 0; it < 32; ++it) { XROUND(it); }
        if (lane < 32) s_cand[w * 32 + lane] = kept;
        __syncthreads();

        uint32_t v0 = s_cand[lane];
        uint32_t v1 = s_cand[64 + lane];
#pragma unroll
        for (int k = 2; k <= 128; k <<= 1) {
#pragma unroll
            for (int j = k >> 1; j > 0; j >>= 1) {
                if (j == 64) {
                    const uint32_t a = v0 > v1 ? v0 : v1;
                    const uint32_t b = v0 > v1 ? v1 : v0;
                    v0 = a; v1 = b;
                } else {
                    const bool jl = (lane & j) == 0;
                    {
                        const uint32_t p = __shfl_xor(v0, j);
                        const bool km = ((lane & k) == 0) == jl;
                        v0 = ((p > v0) == km) ? p : v0;
                    }
                    {
                        const uint32_t p = __shfl_xor(v1, j);
                        const bool km = (((lane + 64) & k) == 0) == jl;
                        v1 = ((p > v1) == km) ? p : v1;
                    }
                }
            }
        }

        const int slotv = 4095 - (int)(v0 & 0xFFFu);
        float pv = 0.f;
        if (lane < 32) pv = __expf(s_union[slotv] - m) * inv;
        const bool kp = (lane < MIN_K) || (pv > (1.0f / 4096.0f));
        float wsum = kp ? pv : 0.f;
#pragma unroll
        for (int o = 32; o; o >>= 1) wsum += __shfl_xor(wsum, o);
        const float wgtl = kp ? pv / (wsum + 1e-9f) : 0.f;
        if (w == 0 && lane < 32 && kp) atomicAdd(&counts[slotv], 1.0f);
        __syncthreads();

        PROJ_AND_OUT(t);
        __syncthreads();   // s_union reuse across fail-list iterations
    }

    // ---- completion + last-block finalize (R6-proven coherence pattern) ----
    __threadfence();
    __syncthreads();
    if (tid == 0) s_last = (atomicAdd(&failcnt[1], 1) == (int)gridDim.x - 1) ? 1 : 0;
    __syncthreads();
    if (s_last) {
        __threadfence();
        float tot = 0.f, act = 0.f, dot = 0.f;
#pragma unroll
        for (int j = 0; j < 16; ++j) {
            const int i = j * 256 + tid;
            const float c  = atomicAdd(&counts[i], 0.f);  // device-coherent read
            const float cs = colsum[i];                   // prior-kernel data
            tot += c;
            act += (c > 0.f) ? 1.f : 0.f;
            dot += cs * c;
        }
#pragma unroll
        for (int o = 32; o; o >>= 1) {
            tot += __shfl_xor(tot, o);
            act += __shfl_xor(act, o);
            dot += __shfl_xor(dot, o);
        }
        if ((tid & 63) == 0) {
            s_tot[tid >> 6] = tot; s_act[tid >> 6] = act; s_dot[tid >> 6] = dot;
        }
        __syncthreads();
        if (tid == 0) {
            const float T  = s_tot[0] + s_tot[1] + s_tot[2] + s_tot[3];
            const float A  = s_act[0] + s_act[1] + s_act[2] + s_act[3];
            const float Dt = s_dot[0] + s_dot[1] + s_dot[2] + s_dot[3];
            out2[0] = Dt / (T + 1e-9f);   // (4096 tokens) x (N=4096) cancel
            out2[1] = A;
        }
    }
}

// ---------------------------------------------------------------------------
extern "C" void kernel_launch(void* const* d_in, const int* in_sizes, int n_in,
                              void* d_out, int out_size, void* d_ws, size_t ws_size,
                              hipStream_t stream) {
    const float* x    = (const float*)d_in[0];
    const float* pool = (const float*)d_in[1];
    const float* w    = (const float*)d_in[2];
    float* out = (float*)d_out;

    // workspace layout (~56.1 MB total)
    const size_t MB = 1024 * 1024;
    char* ws = (char*)d_ws;
    float*     colsum   = (float*)ws;                              // 16 KB
    float*     counts   = (float*)(ws + 16 * 1024);                // 16 KB
    float2*    minv     = (float2*)(ws + 32 * 1024);               // 32 KB
    int*       failcnt  = (int*)(ws + 64 * 1024);                  // [0]=cnt [1]=done
    int*       faillist = (int*)(ws + 68 * 1024);                  // 16 KB
    uint32_t*  poolh    = (uint32_t*)(ws + 128 * 1024);            // 8 MB
    _Float16*  Apack    = (_Float16*)(ws + 128 * 1024 + 8 * MB);   // 8 MB
    _Float16*  Bpack    = (_Float16*)(ws + 128 * 1024 + 16 * MB);  // 8 MB
    _Float16*  logits   = (_Float16*)(ws + 128 * 1024 + 24 * MB);  // 32 MB (f16)

    pack_all<<<7168, 256, 0, stream>>>(x, w, pool, Apack, Bpack, poolh,
                                       colsum, failcnt);

    gemm256<<<16 * 16, 512, 0, stream>>>(Apack, Bpack, logits, 16);

    router_kernel<<<N_TOKENS, 256, 0, stream>>>(logits, Apack, poolh, out,
                                                minv, counts, failcnt, faillist);

    colsum_lg<<<dim3(NUM_SLOTS / 1024, N_TOKENS / 32), 256, 0, stream>>>(
        logits, minv, colsum);

    fixup_fin<<<64, 256, 0, stream>>>(logits, Apack, poolh, out, minv,
                                      counts, colsum, failcnt, faillist,
                                      out + (out_size - 2));
}

// Round 10
// 145.234 us; speedup vs baseline: 1.0340x; 1.0340x over previous
//
#include <hip/hip_runtime.h>
#include <math.h>
#include <stdint.h>

#define D_MODEL   1024
#define NUM_SLOTS 4096
#define N_TOKENS  4096   // 4 * 1024
#define MIN_K     8
#define MAX_K     32
#define KP        1024   // single-f16 K
#define NSTEP     32     // KP / 32

typedef _Float16 f16x8 __attribute__((ext_vector_type(8)));
typedef _Float16 f16x4 __attribute__((ext_vector_type(4)));
typedef _Float16 h2    __attribute__((ext_vector_type(2)));
typedef float    f32x4 __attribute__((ext_vector_type(4)));

__device__ __forceinline__ void gload16(const void* g, void* l) {
    __builtin_amdgcn_global_load_lds((const __attribute__((address_space(1))) void*)g,
                                     (__attribute__((address_space(3))) void*)l,
                                     16, 0, 0);
}

__device__ __forceinline__ h2 as_h2(uint32_t u) {
    union { uint32_t u; h2 h; } c; c.u = u; return c.h;
}
__device__ __forceinline__ uint32_t h2pack(float a, float b) {
    union { uint32_t u; h2 h; } c; c.h.x = (_Float16)a; c.h.y = (_Float16)b; return c.u;
}

// ordered-uint transform: u32 order == float order (all finite values)
__device__ __forceinline__ uint32_t ford(float f) {
    uint32_t b = __float_as_uint(f);
    return b ^ (uint32_t)(((int32_t)b >> 31) | 0x80000000);
}

// ---------------------------------------------------------------------------
// pack_all: fused  (1) x f32 -> A f16 [4096][1024]
//                  (2) w f32 [1024][4096] -> B^T f16 [4096][1024]
//                  (3) pool f32 -> f16 packed pairs
//                  (4) clear colsum+counts+failcnt+done
// ---------------------------------------------------------------------------
__global__ __launch_bounds__(256) void pack_all(const float* __restrict__ x,
                                                const float* __restrict__ w,
                                                const float* __restrict__ pool,
                                                _Float16* __restrict__ A,
                                                _Float16* __restrict__ BT,
                                                uint32_t* __restrict__ poolh,
                                                float* __restrict__ clr,
                                                int* __restrict__ failcnt) {
    __shared__ float tile[64][65];
    const int bid = blockIdx.x;
    const int tid = threadIdx.x;

    if (bid < 4096) {
        // ---- pack_x: 4 elems/thread ----
        if (bid < 32) clr[bid * 256 + tid] = 0.f;   // colsum+counts clear
        if (bid == 32 && tid == 0) { failcnt[0] = 0; failcnt[1] = 0; }
        const int i = bid * 256 + tid;              // quad index, 1M total
        const float4 v = reinterpret_cast<const float4*>(x)[i];
        const int t = i >> 8;                       // 256 quads per 1024-row
        const int d = (i & 255) << 2;
        f16x4 hi;
        hi[0] = (_Float16)v.x; hi[1] = (_Float16)v.y;
        hi[2] = (_Float16)v.z; hi[3] = (_Float16)v.w;
        *(f16x4*)(A + (size_t)t * KP + d) = hi;
    } else if (bid < 5120) {
        // ---- pack_wt: 64x64 transpose tile ----
        const int b2 = bid - 4096;
        const int n0 = (b2 & 63) * 64;
        const int k0 = (b2 >> 6) * 64;
        {
            const int c  = tid & 63;
            const int r0 = tid >> 6;       // 0..3
#pragma unroll
            for (int i = 0; i < 16; ++i) {
                const int r = r0 * 16 + i;
                tile[r][c] = w[(size_t)(k0 + r) * NUM_SLOTS + n0 + c];
            }
        }
        __syncthreads();
        const int nl  = tid >> 2;          // 0..63
        const int kl0 = (tid & 3) * 16;    // 0,16,32,48
        _Float16* rowp = BT + (size_t)(n0 + nl) * KP + k0;
#pragma unroll
        for (int j4 = 0; j4 < 16; j4 += 4) {
            f16x4 hi;
#pragma unroll
            for (int u = 0; u < 4; ++u)
                hi[u] = (_Float16)tile[kl0 + j4 + u][nl];
            *(f16x4*)(rowp + kl0 + j4) = hi;
        }
    } else {
        // ---- pack_pool: 8 elems/thread -> packed f16 pairs ----
        const size_t i = (size_t)(bid - 5120) * 256 + tid;
        const float4* s4 = reinterpret_cast<const float4*>(pool);
        const float4 a = s4[2 * i];
        const float4 b = s4[2 * i + 1];
        uint4 u;
        u.x = h2pack(a.x, a.y);
        u.y = h2pack(a.z, a.w);
        u.z = h2pack(b.x, b.y);
        u.w = h2pack(b.z, b.w);
        reinterpret_cast<uint4*>(poolh)[i] = u;
    }
}

// ---------------------------------------------------------------------------
// gemm256: 256x256 tile, BK=32, 8 waves, counted vmcnt, LDS slot-swizzle,
// setprio, XCD-aware block swizzle. Output logits stored as f16 (32 MB).
// ---------------------------------------------------------------------------
#define STAGE_A(NXT, S2) \
    gload16(gA0 + (size_t)(S2) * 32, (void*)(AsF + (NXT) * 8192 + tid * 8)); \
    gload16(gA1 + (size_t)(S2) * 32, (void*)(AsF + (NXT) * 8192 + 4096 + tid * 8));
#define STAGE_B(NXT, S2) \
    gload16(gB0 + (size_t)(S2) * 32, (void*)(BsF + (NXT) * 8192 + tid * 8)); \
    gload16(gB1 + (size_t)(S2) * 32, (void*)(BsF + (NXT) * 8192 + 4096 + tid * 8));

#define MM(AF, M) \
    acc[M][0] = __builtin_amdgcn_mfma_f32_16x16x32_f16(AF, bf0, acc[M][0], 0, 0, 0); \
    acc[M][1] = __builtin_amdgcn_mfma_f32_16x16x32_f16(AF, bf1, acc[M][1], 0, 0, 0); \
    acc[M][2] = __builtin_amdgcn_mfma_f32_16x16x32_f16(AF, bf2, acc[M][2], 0, 0, 0); \
    acc[M][3] = __builtin_amdgcn_mfma_f32_16x16x32_f16(AF, bf3, acc[M][3], 0, 0, 0);

#define GSTEP(S, CUR, NXT) do { \
    const _Float16* a_ = AsF + (CUR) * 8192; \
    const _Float16* b_ = BsF + (CUR) * 8192; \
    f16x8 bf0 = *(const f16x8*)(b_ + offB0); \
    f16x8 bf1 = *(const f16x8*)(b_ + offB1); \
    f16x8 bf2 = *(const f16x8*)(b_ + offB2); \
    f16x8 bf3 = *(const f16x8*)(b_ + offB3); \
    f16x8 a0 = *(const f16x8*)(a_ + offA0); \
    f16x8 a1 = *(const f16x8*)(a_ + offA1); \
    f16x8 a2 = *(const f16x8*)(a_ + offA2); \
    f16x8 a3 = *(const f16x8*)(a_ + offA3); \
    if ((S) + 2 < NSTEP) { STAGE_A(NXT, (S) + 2) } \
    asm volatile("" ::: "memory"); \
    __builtin_amdgcn_s_barrier(); \
    __builtin_amdgcn_s_setprio(1); \
    MM(a0, 0) MM(a1, 1) MM(a2, 2) MM(a3, 3) \
    __builtin_amdgcn_s_setprio(0); \
    asm volatile("" ::: "memory"); \
    __builtin_amdgcn_s_barrier(); \
    a0 = *(const f16x8*)(a_ + offA4); \
    a1 = *(const f16x8*)(a_ + offA5); \
    a2 = *(const f16x8*)(a_ + offA6); \
    a3 = *(const f16x8*)(a_ + offA7); \
    if ((S) + 2 < NSTEP) { STAGE_B(NXT, (S) + 2) } \
    asm volatile("" ::: "memory"); \
    __builtin_amdgcn_s_barrier(); \
    __builtin_amdgcn_s_setprio(1); \
    MM(a0, 4) MM(a1, 5) MM(a2, 6) MM(a3, 7) \
    __builtin_amdgcn_s_setprio(0); \
    if ((S) < NSTEP - 2) { asm volatile("s_waitcnt vmcnt(4)" ::: "memory"); } \
    else                 { asm volatile("s_waitcnt vmcnt(0)" ::: "memory"); } \
    __builtin_amdgcn_s_barrier(); \
} while (0)

__global__ __launch_bounds__(512, 2) void gemm256(const _Float16* __restrict__ A,
                                                  const _Float16* __restrict__ BT,
                                                  _Float16* __restrict__ C,
                                                  int nbm) {
    __shared__ _Float16 AsF[4 * 8192];   // 4 bufs x [256 rows][32 k] f16 = 64KB
    __shared__ _Float16 BsF[4 * 8192];   // 64KB
    const int tid  = threadIdx.x;
    const int lane = tid & 63;
    const int wv   = tid >> 6;           // 0..7
    const int wm   = wv >> 2;            // 0..1
    const int wn   = wv & 3;             // 0..3

    // ---- XCD-aware decode: grid 16x16 -> each XCD owns a 4x8 region ----
    int brow, bcol;
    {
        const int bid = blockIdx.x;
        if (nbm == 16) {
            const int xcd = bid & 7;
            const int l   = bid >> 3;          // 0..31
            brow = (xcd & 3) * 4 + (l & 3);
            bcol = (xcd >> 2) * 8 + (l >> 2);
        } else {
            brow = bid >> 4;
            bcol = bid & 15;
        }
    }
    const size_t bm = (size_t)brow * 256;
    const size_t bn = (size_t)bcol * 256;

    const int rowA = tid >> 2;               // 0..127 (row within half)
    const int slot = tid & 3;                // 16B slot within 64B row
    const int sswz = slot ^ ((rowA >> 1) & 3);
    const _Float16* gA0 = A  + (bm + rowA) * (size_t)KP + sswz * 8;
    const _Float16* gA1 = A  + (bm + rowA + 128) * (size_t)KP + sswz * 8;
    const _Float16* gB0 = BT + (bn + rowA) * (size_t)KP + sswz * 8;
    const _Float16* gB1 = BT + (bn + rowA + 128) * (size_t)KP + sswz * 8;

    int offA0, offA1, offA2, offA3, offA4, offA5, offA6, offA7;
    int offB0, offB1, offB2, offB3;
    {
        const int r15 = lane & 15, ls = lane >> 4;
#define AOFF(M) (((wm) * 128 + (M) * 16 + r15) * 32 + \
                 ((ls ^ ((((wm) * 128 + (M) * 16 + r15) >> 1) & 3)) * 8))
#define BOFF(N) (((wn) * 64 + (N) * 16 + r15) * 32 + \
                 ((ls ^ ((((wn) * 64 + (N) * 16 + r15) >> 1) & 3)) * 8))
        offA0 = AOFF(0); offA1 = AOFF(1); offA2 = AOFF(2); offA3 = AOFF(3);
        offA4 = AOFF(4); offA5 = AOFF(5); offA6 = AOFF(6); offA7 = AOFF(7);
        offB0 = BOFF(0); offB1 = BOFF(1); offB2 = BOFF(2); offB3 = BOFF(3);
#undef AOFF
#undef BOFF
    }

    f32x4 acc[8][4] = {};

    STAGE_A(0, 0) STAGE_B(0, 0)
    STAGE_A(1, 1) STAGE_B(1, 1)
    asm volatile("s_waitcnt vmcnt(4)" ::: "memory");
    __builtin_amdgcn_s_barrier();

    for (int s4 = 0; s4 < NSTEP; s4 += 4) {
        GSTEP(s4 + 0, 0, 2);
        GSTEP(s4 + 1, 1, 3);
        GSTEP(s4 + 2, 2, 0);
        GSTEP(s4 + 3, 3, 1);
    }

    const size_t crow = bm + wm * 128 + ((lane >> 4) << 2);
    const size_t ccol = bn + wn * 64 + (lane & 15);
#pragma unroll
    for (int m = 0; m < 8; ++m)
#pragma unroll
        for (int r = 0; r < 4; ++r) {
            _Float16* cp = C + (crow + m * 16 + r) * (size_t)NUM_SLOTS + ccol;
#pragma unroll
            for (int n = 0; n < 4; ++n) cp[n * 16] = (_Float16)acc[m][n][r];
        }
}

// ---------------------------------------------------------------------------
// router v11: R8 fast path + tie-tolerant validity (R9) + T5 setprio around
// the latency-serial region (softmax reductions, extraction, bitonic).
// Router blocks are independent & phase-staggered per CU -> setprio regime
// where it measured +4-7% (attn analog, m191).
// ---------------------------------------------------------------------------
#define RECOMP(G, A, B, Cc, D) do { \
    uint32_t t0 = (msk & (1u << (A)))  ? k##A  : 0u; \
    uint32_t t1 = (msk & (1u << (B)))  ? k##B  : 0u; \
    uint32_t t2 = (msk & (1u << (Cc))) ? k##Cc : 0u; \
    uint32_t t3 = (msk & (1u << (D)))  ? k##D  : 0u; \
    t0 = t0 > t1 ? t0 : t1; t2 = t2 > t3 ? t2 : t3; \
    gm##G = t0 > t2 ? t0 : t2; } while (0)

#define XROUND(IT) do { \
    uint32_t best = gm0; \
    if (gm1 > best) best = gm1; \
    if (gm2 > best) best = gm2; \
    if (gm3 > best) best = gm3; \
    uint32_t wb = best; \
    _Pragma("unroll") \
    for (int o = 32; o; o >>= 1) { \
        const uint32_t p = __shfl_xor(wb, o); \
        if (p > wb) wb = p; \
    } \
    if (lane == (IT)) kept = wb; \
    if (best == wb) { \
        const int idx = 4095 - (int)(wb & 0xFFFu); \
        const int rem = idx - kb; \
        const int jj = rem >> 8; \
        msk &= ~(1u << (4 * jj + (rem & 3))); \
        switch (jj) { \
            case 0:  RECOMP(0, 0, 1, 2, 3); break; \
            case 1:  RECOMP(1, 4, 5, 6, 7); break; \
            case 2:  RECOMP(2, 8, 9, 10, 11); break; \
            default: RECOMP(3, 12, 13, 14, 15); break; \
        } \
    } \
} while (0)

// load f16 logit quad groups with the SAME slot mapping as the f32 version
#define LOADLV(TOK) \
    const uint2* lrow2 = reinterpret_cast<const uint2*>(logits + (size_t)(TOK) * NUM_SLOTS + wseg); \
    float4 lv0, lv1, lv2, lv3; \
    { \
        const uint2 u0 = lrow2[lane]; \
        const uint2 u1 = lrow2[lane + 64]; \
        const uint2 u2 = lrow2[lane + 128]; \
        const uint2 u3 = lrow2[lane + 192]; \
        h2 ha, hb; \
        ha = as_h2(u0.x); hb = as_h2(u0.y); \
        lv0 = make_float4((float)ha.x, (float)ha.y, (float)hb.x, (float)hb.y); \
        ha = as_h2(u1.x); hb = as_h2(u1.y); \
        lv1 = make_float4((float)ha.x, (float)ha.y, (float)hb.x, (float)hb.y); \
        ha = as_h2(u2.x); hb = as_h2(u2.y); \
        lv2 = make_float4((float)ha.x, (float)ha.y, (float)hb.x, (float)hb.y); \
        ha = as_h2(u3.x); hb = as_h2(u3.y); \
        lv3 = make_float4((float)ha.x, (float)ha.y, (float)hb.x, (float)hb.y); \
    }

#define MAKEKEYS(E0, E1, E2, E3) \
    k0  = (ford((E0).x) & 0xFFFFF000u) | (uint32_t)(4095 - (kb + 0)); \
    k1  = (ford((E0).y) & 0xFFFFF000u) | (uint32_t)(4095 - (kb + 1)); \
    k2  = (ford((E0).z) & 0xFFFFF000u) | (uint32_t)(4095 - (kb + 2)); \
    k3  = (ford((E0).w) & 0xFFFFF000u) | (uint32_t)(4095 - (kb + 3)); \
    k4  = (ford((E1).x) & 0xFFFFF000u) | (uint32_t)(4095 - (kb + 256)); \
    k5  = (ford((E1).y) & 0xFFFFF000u) | (uint32_t)(4095 - (kb + 257)); \
    k6  = (ford((E1).z) & 0xFFFFF000u) | (uint32_t)(4095 - (kb + 258)); \
    k7  = (ford((E1).w) & 0xFFFFF000u) | (uint32_t)(4095 - (kb + 259)); \
    k8  = (ford((E2).x) & 0xFFFFF000u) | (uint32_t)(4095 - (kb + 512)); \
    k9  = (ford((E2).y) & 0xFFFFF000u) | (uint32_t)(4095 - (kb + 513)); \
    k10 = (ford((E2).z) & 0xFFFFF000u) | (uint32_t)(4095 - (kb + 514)); \
    k11 = (ford((E2).w) & 0xFFFFF000u) | (uint32_t)(4095 - (kb + 515)); \
    k12 = (ford((E3).x) & 0xFFFFF000u) | (uint32_t)(4095 - (kb + 768)); \
    k13 = (ford((E3).y) & 0xFFFFF000u) | (uint32_t)(4095 - (kb + 769)); \
    k14 = (ford((E3).z) & 0xFFFFF000u) | (uint32_t)(4095 - (kb + 770)); \
    k15 = (ford((E3).w) & 0xFFFFF000u) | (uint32_t)(4095 - (kb + 771));

// fused proj + cross-wave out merge (f16 pool + f16 x from Apack)
#define PROJ_AND_OUT(TOK) do { \
    const uint4* xA = reinterpret_cast<const uint4*>(Af + (size_t)(TOK) * D_MODEL); \
    const uint4 xq0 = xA[lane]; \
    const uint4 xq1 = xA[lane + 64]; \
    const h2 xh0 = as_h2(xq0.x), xh1 = as_h2(xq0.y); \
    const h2 xh2 = as_h2(xq0.z), xh3 = as_h2(xq0.w); \
    const h2 xh4 = as_h2(xq1.x), xh5 = as_h2(xq1.y); \
    const h2 xh6 = as_h2(xq1.z), xh7 = as_h2(xq1.w); \
    float4 oa0 = {0,0,0,0}, ob0 = {0,0,0,0}, oa1 = {0,0,0,0}, ob1 = {0,0,0,0}; \
    _Pragma("unroll") \
    for (int ii = 0; ii < 8; ++ii) { \
        const int   i     = w * 8 + ii; \
        const int   slotg = __shfl(slotv, i); \
        const float wgt   = __shfl(wgtl, i); \
        if (wgt != 0.f) { \
            const uint4* pr = reinterpret_cast<const uint4*>(poolh + (size_t)slotg * (D_MODEL / 2)); \
            const uint4 q0 = pr[lane]; \
            const uint4 q1 = pr[lane + 64]; \
            const h2 p0 = as_h2(q0.x), p1 = as_h2(q0.y); \
            const h2 p2 = as_h2(q0.z), p3 = as_h2(q0.w); \
            const h2 p4 = as_h2(q1.x), p5 = as_h2(q1.y); \
            const h2 p6 = as_h2(q1.z), p7 = as_h2(q1.w); \
            h2 acc2 = xh0 * p0; \
            acc2 = xh1 * p1 + acc2; \
            acc2 = xh2 * p2 + acc2; \
            acc2 = xh3 * p3 + acc2; \
            acc2 = xh4 * p4 + acc2; \
            acc2 = xh5 * p5 + acc2; \
            acc2 = xh6 * p6 + acc2; \
            acc2 = xh7 * p7 + acc2; \
            float d = (float)acc2.x + (float)acc2.y; \
            _Pragma("unroll") \
            for (int o = 32; o; o >>= 1) d += __shfl_xor(d, o); \
            const float wp = d * wgt; \
            oa0.x = fmaf(wp, (float)p0.x, oa0.x); oa0.y = fmaf(wp, (float)p0.y, oa0.y); \
            oa0.z = fmaf(wp, (float)p1.x, oa0.z); oa0.w = fmaf(wp, (float)p1.y, oa0.w); \
            ob0.x = fmaf(wp, (float)p2.x, ob0.x); ob0.y = fmaf(wp, (float)p2.y, ob0.y); \
            ob0.z = fmaf(wp, (float)p3.x, ob0.z); ob0.w = fmaf(wp, (float)p3.y, ob0.w); \
            oa1.x = fmaf(wp, (float)p4.x, oa1.x); oa1.y = fmaf(wp, (float)p4.y, oa1.y); \
            oa1.z = fmaf(wp, (float)p5.x, oa1.z); oa1.w = fmaf(wp, (float)p5.y, oa1.w); \
            ob1.x = fmaf(wp, (float)p6.x, ob1.x); ob1.y = fmaf(wp, (float)p6.y, ob1.y); \
            ob1.z = fmaf(wp, (float)p7.x, ob1.z); ob1.w = fmaf(wp, (float)p7.y, ob1.w); \
        } \
    } \
    { \
        float4* op = reinterpret_cast<float4*>(s_union + w * 1024); \
        op[2 * lane]       = oa0; \
        op[2 * lane + 1]   = ob0; \
        op[2 * lane + 128] = oa1; \
        op[2 * lane + 129] = ob1; \
    } \
    __syncthreads(); \
    float4 r = {0, 0, 0, 0}; \
    _Pragma("unroll") \
    for (int ww = 0; ww < 4; ++ww) { \
        const float4 vv = reinterpret_cast<const float4*>(s_union + ww * 1024)[tid]; \
        r.x += vv.x; r.y += vv.y; r.z += vv.z; r.w += vv.w; \
    } \
    reinterpret_cast<float4*>(out + (size_t)(TOK) * D_MODEL)[tid] = r; \
} while (0)

__global__ __launch_bounds__(256) void router_kernel(
    const _Float16* __restrict__ logits,     // [4096][4096] f16
    const _Float16* __restrict__ Af,         // Apack: x as f16 [4096][1024]
    const uint32_t* __restrict__ poolh,      // [4096][512] packed f16 pairs
    float* __restrict__ out,                 // [4096][1024]
    float2* __restrict__ minv,               // [4096] (m, inv) per token
    float* __restrict__ counts,
    int* __restrict__ failcnt,
    int* __restrict__ faillist) {
    __shared__ float    s_union[NUM_SLOTS];  // logit table, then out-partials
    __shared__ uint32_t s_cand[68];          // [0..63] candidates, [64..67] rmax
    __shared__ float    s_redv[4];

    const int tid  = threadIdx.x;
    const int w    = tid >> 6;
    const int lane = tid & 63;
    const int wseg = w << 10;
    const int t    = blockIdx.x;

    LOADLV(t)

    reinterpret_cast<float4*>(s_union + wseg)[lane]       = lv0;
    reinterpret_cast<float4*>(s_union + wseg)[lane + 64]  = lv1;
    reinterpret_cast<float4*>(s_union + wseg)[lane + 128] = lv2;
    reinterpret_cast<float4*>(s_union + wseg)[lane + 192] = lv3;

    // ---- T5: prioritize the latency-serial region (reduce chains,
    //      extraction, bitonic) over co-resident blocks' memory phases ----
    __builtin_amdgcn_s_setprio(1);

    float lmax = fmaxf(fmaxf(fmaxf(lv0.x, lv0.y), fmaxf(lv0.z, lv0.w)),
                       fmaxf(fmaxf(lv1.x, lv1.y), fmaxf(lv1.z, lv1.w)));
    lmax = fmaxf(lmax, fmaxf(fmaxf(lv2.x, lv2.y), fmaxf(lv2.z, lv2.w)));
    lmax = fmaxf(lmax, fmaxf(fmaxf(lv3.x, lv3.y), fmaxf(lv3.z, lv3.w)));
#pragma unroll
    for (int o = 32; o; o >>= 1) lmax = fmaxf(lmax, __shfl_xor(lmax, o));
    if (lane == 0) s_redv[w] = lmax;
    __syncthreads();
    const float m = fmaxf(fmaxf(s_redv[0], s_redv[1]), fmaxf(s_redv[2], s_redv[3]));
    __syncthreads();

    // ---- e = exp(l - m); denom ----
    float lsum;
    {
        float4 ev0, ev1, ev2, ev3;
        ev0.x = __expf(lv0.x - m); ev0.y = __expf(lv0.y - m);
        ev0.z = __expf(lv0.z - m); ev0.w = __expf(lv0.w - m);
        ev1.x = __expf(lv1.x - m); ev1.y = __expf(lv1.y - m);
        ev1.z = __expf(lv1.z - m); ev1.w = __expf(lv1.w - m);
        ev2.x = __expf(lv2.x - m); ev2.y = __expf(lv2.y - m);
        ev2.z = __expf(lv2.z - m); ev2.w = __expf(lv2.w - m);
        ev3.x = __expf(lv3.x - m); ev3.y = __expf(lv3.y - m);
        ev3.z = __expf(lv3.z - m); ev3.w = __expf(lv3.w - m);
        lsum = (ev0.x + ev0.y + ev0.z + ev0.w) + (ev1.x + ev1.y + ev1.z + ev1.w) +
               (ev2.x + ev2.y + ev2.z + ev2.w) + (ev3.x + ev3.y + ev3.z + ev3.w);
    }
#pragma unroll
    for (int o = 32; o; o >>= 1) lsum += __shfl_xor(lsum, o);
    if (lane == 0) s_redv[w] = lsum;
    __syncthreads();
    const float inv = 1.0f / (s_redv[0] + s_redv[1] + s_redv[2] + s_redv[3]);
    if (tid == 0) minv[t] = make_float2(m, inv);

    // ---- named u32 keys ----
    const int kb = wseg + 4 * lane;
    uint32_t k0, k1, k2, k3, k4, k5, k6, k7;
    uint32_t k8, k9, k10, k11, k12, k13, k14, k15;
    MAKEKEYS(lv0, lv1, lv2, lv3)

    uint32_t msk = 0xFFFFu;
    uint32_t gm0, gm1, gm2, gm3;
    RECOMP(0, 0, 1, 2, 3); RECOMP(1, 4, 5, 6, 7);
    RECOMP(2, 8, 9, 10, 11); RECOMP(3, 12, 13, 14, 15);

    // ---- fast path: 16 extraction rounds per wave ----
    uint32_t kept = 0;
    for (int it = 0; it < 16; ++it) { XROUND(it); }

    // wave's largest remaining key -> s_cand[64+w]
    {
        uint32_t best = gm0;
        if (gm1 > best) best = gm1;
        if (gm2 > best) best = gm2;
        if (gm3 > best) best = gm3;
#pragma unroll
        for (int o = 32; o; o >>= 1) {
            const uint32_t p = __shfl_xor(best, o);
            if (p > best) best = p;
        }
        if (lane == 0) s_cand[64 + w] = best;
    }
    if (lane < 16) s_cand[w * 16 + lane] = kept;
    __syncthreads();

    // ---- 64-wide bitonic descending sort of the 4x16 candidates ----
    uint32_t v0 = s_cand[lane];
#pragma unroll
    for (int k = 2; k <= 64; k <<= 1) {
#pragma unroll
        for (int j = k >> 1; j > 0; j >>= 1) {
            const bool jl = (lane & j) == 0;
            const uint32_t p = __shfl_xor(v0, j);
            const bool km = ((lane & k) == 0) == jl;
            v0 = ((p > v0) == km) ? p : v0;
        }
    }

    // ---- validity (TIE-TOLERANT, R9): fail only if a remaining key's
    //      VALUE strictly beats the 32nd candidate's VALUE ----
    const uint32_t th = __shfl(v0, 31);
    uint32_t mw = s_cand[64];
    {
        const uint32_t m1 = s_cand[65], m2 = s_cand[66], m3 = s_cand[67];
        if (m1 > mw) mw = m1;
        if (m2 > mw) mw = m2;
        if (m3 > mw) mw = m3;
    }
    if ((mw & 0xFFFFF000u) > (th & 0xFFFFF000u)) {   // block-uniform; rare
        __builtin_amdgcn_s_setprio(0);
        if (tid == 0) {
            const int fi = atomicAdd(failcnt, 1);
            faillist[fi] = t;
        }
        return;                          // fixup kernel handles this token
    }

    // ---- ranks 0..31 in v0 lanes 0..31; recover p from LDS logit table ----
    const int slotv = 4095 - (int)(v0 & 0xFFFu);
    float pv = 0.f;
    if (lane < 32) pv = __expf(s_union[slotv] - m) * inv;
    const bool kp = (lane < MIN_K) || (pv > (1.0f / 4096.0f));  // lanes>=32: false
    float wsum = kp ? pv : 0.f;
#pragma unroll
    for (int o = 32; o; o >>= 1) wsum += __shfl_xor(wsum, o);
    const float wgtl = kp ? pv / (wsum + 1e-9f) : 0.f;
    if (w == 0 && lane < 32 && kp) atomicAdd(&counts[slotv], 1.0f);

    __builtin_amdgcn_s_setprio(0);   // memory-heavy proj runs at normal prio
    __syncthreads();   // all s_union (logit) reads done before reuse

    PROJ_AND_OUT(t);
}

// ---------------------------------------------------------------------------
// colsum_lg: colsum[n] = sum_t exp(logit[t][n] - m_t) * inv_t  (f16 logits)
// R8-proven grid (4, 64): 256 blocks, 64-token inner loop.
// ---------------------------------------------------------------------------
__global__ __launch_bounds__(256) void colsum_lg(const _Float16* __restrict__ logits,
                                                 const float2* __restrict__ minv,
                                                 float* __restrict__ colsum) {
    const int tid = threadIdx.x;
    const int s0  = blockIdx.x * 1024;
    const int t0  = blockIdx.y * 64;
    float a0 = 0.f, a1 = 0.f, a2 = 0.f, a3 = 0.f;
    for (int t = 0; t < 64; ++t) {
        const float2 mv = minv[t0 + t];
        const uint2 v = reinterpret_cast<const uint2*>(
            logits + (size_t)(t0 + t) * NUM_SLOTS + s0)[tid];
        const h2 va = as_h2(v.x), vb = as_h2(v.y);
        a0 = fmaf(__expf((float)va.x - mv.x), mv.y, a0);
        a1 = fmaf(__expf((float)va.y - mv.x), mv.y, a1);
        a2 = fmaf(__expf((float)vb.x - mv.x), mv.y, a2);
        a3 = fmaf(__expf((float)vb.y - mv.x), mv.y, a3);
    }
    const int c = s0 + 4 * tid;
    atomicAdd(&colsum[c + 0], a0);
    atomicAdd(&colsum[c + 1], a1);
    atomicAdd(&colsum[c + 2], a2);
    atomicAdd(&colsum[c + 3], a3);
}

// ---------------------------------------------------------------------------
// fixup_fin: exact full path for failed tokens (64 blocks stride fail-list)
// + last-block finalize (done counter at failcnt[1]). Runs AFTER colsum_lg.
// ---------------------------------------------------------------------------
__global__ __launch_bounds__(256) void fixup_fin(
    const _Float16* __restrict__ logits,
    const _Float16* __restrict__ Af,
    const uint32_t* __restrict__ poolh,
    float* __restrict__ out,
    const float2* __restrict__ minv,
    float* __restrict__ counts,
    float* __restrict__ colsum,
    int* __restrict__ failcnt,
    const int* __restrict__ faillist,
    float* __restrict__ out2) {
    __shared__ float    s_union[NUM_SLOTS];
    __shared__ uint32_t s_cand[128];
    __shared__ float    s_tot[4], s_act[4], s_dot[4];
    __shared__ int      s_last;

    const int tid  = threadIdx.x;
    const int w    = tid >> 6;
    const int lane = tid & 63;
    const int wseg = w << 10;
    const int n    = failcnt[0];

    for (int fi = blockIdx.x; fi < n; fi += gridDim.x) {
        const int t = faillist[fi];
        LOADLV(t)
        reinterpret_cast<float4*>(s_union + wseg)[lane]       = lv0;
        reinterpret_cast<float4*>(s_union + wseg)[lane + 64]  = lv1;
        reinterpret_cast<float4*>(s_union + wseg)[lane + 128] = lv2;
        reinterpret_cast<float4*>(s_union + wseg)[lane + 192] = lv3;
        const float2 mv = minv[t];
        const float m = mv.x, inv = mv.y;

        const int kb = wseg + 4 * lane;
        uint32_t k0, k1, k2, k3, k4, k5, k6, k7;
        uint32_t k8, k9, k10, k11, k12, k13, k14, k15;
        MAKEKEYS(lv0, lv1, lv2, lv3)

        uint32_t msk = 0xFFFFu;
        uint32_t gm0, gm1, gm2, gm3;
        RECOMP(0, 0, 1, 2, 3); RECOMP(1, 4, 5, 6, 7);
        RECOMP(2, 8, 9, 10, 11); RECOMP(3, 12, 13, 14, 15);

        uint32_t kept = 0;
        for (int it = 0; it < 32; ++it) { XROUND(it); }
        if (lane < 32) s_cand[w * 32 + lane] = kept;
        __syncthreads();

        uint32_t v0 = s_cand[lane];
        uint32_t v1 = s_cand[64 + lane];
#pragma unroll
        for (int k = 2; k <= 128; k <<= 1) {
#pragma unroll
            for (int j = k >> 1; j > 0; j >>= 1) {
                if (j == 64) {
                    const uint32_t a = v0 > v1 ? v0 : v1;
                    const uint32_t b = v0 > v1 ? v1 : v0;
                    v0 = a; v1 = b;
                } else {
                    const bool jl = (lane & j) == 0;
                    {
                        const uint32_t p = __shfl_xor(v0, j);
                        const bool km = ((lane & k) == 0) == jl;
                        v0 = ((p > v0) == km) ? p : v0;
                    }
                    {
                        const uint32_t p = __shfl_xor(v1, j);
                        const bool km = (((lane + 64) & k) == 0) == jl;
                        v1 = ((p > v1) == km) ? p : v1;
                    }
                }
            }
        }

        const int slotv = 4095 - (int)(v0 & 0xFFFu);
        float pv = 0.f;
        if (lane < 32) pv = __expf(s_union[slotv] - m) * inv;
        const bool kp = (lane < MIN_K) || (pv > (1.0f / 4096.0f));
        float wsum = kp ? pv : 0.f;
#pragma unroll
        for (int o = 32; o; o >>= 1) wsum += __shfl_xor(wsum, o);
        const float wgtl = kp ? pv / (wsum + 1e-9f) : 0.f;
        if (w == 0 && lane < 32 && kp) atomicAdd(&counts[slotv], 1.0f);
        __syncthreads();

        PROJ_AND_OUT(t);
        __syncthreads();   // s_union reuse across fail-list iterations
    }

    // ---- completion + last-block finalize (R6-proven coherence pattern) ----
    __threadfence();
    __syncthreads();
    if (tid == 0) s_last = (atomicAdd(&failcnt[1], 1) == (int)gridDim.x - 1) ? 1 : 0;
    __syncthreads();
    if (s_last) {
        __threadfence();
        float tot = 0.f, act = 0.f, dot = 0.f;
#pragma unroll
        for (int j = 0; j < 16; ++j) {
            const int i = j * 256 + tid;
            const float c  = atomicAdd(&counts[i], 0.f);  // device-coherent read
            const float cs = colsum[i];                   // prior-kernel data
            tot += c;
            act += (c > 0.f) ? 1.f : 0.f;
            dot += cs * c;
        }
#pragma unroll
        for (int o = 32; o; o >>= 1) {
            tot += __shfl_xor(tot, o);
            act += __shfl_xor(act, o);
            dot += __shfl_xor(dot, o);
        }
        if ((tid & 63) == 0) {
            s_tot[tid >> 6] = tot; s_act[tid >> 6] = act; s_dot[tid >> 6] = dot;
        }
        __syncthreads();
        if (tid == 0) {
            const float T  = s_tot[0] + s_tot[1] + s_tot[2] + s_tot[3];
            const float A  = s_act[0] + s_act[1] + s_act[2] + s_act[3];
            const float Dt = s_dot[0] + s_dot[1] + s_dot[2] + s_dot[3];
            out2[0] = Dt / (T + 1e-9f);   // (4096 tokens) x (N=4096) cancel
            out2[1] = A;
        }
    }
}

// ---------------------------------------------------------------------------
extern "C" void kernel_launch(void* const* d_in, const int* in_sizes, int n_in,
                              void* d_out, int out_size, void* d_ws, size_t ws_size,
                              hipStream_t stream) {
    const float* x    = (const float*)d_in[0];
    const float* pool = (const float*)d_in[1];
    const float* w    = (const float*)d_in[2];
    float* out = (float*)d_out;

    // workspace layout (~56.1 MB total)
    const size_t MB = 1024 * 1024;
    char* ws = (char*)d_ws;
    float*     colsum   = (float*)ws;                              // 16 KB
    float*     counts   = (float*)(ws + 16 * 1024);                // 16 KB
    float2*    minv     = (float2*)(ws + 32 * 1024);               // 32 KB
    int*       failcnt  = (int*)(ws + 64 * 1024);                  // [0]=cnt [1]=done
    int*       faillist = (int*)(ws + 68 * 1024);                  // 16 KB
    uint32_t*  poolh    = (uint32_t*)(ws + 128 * 1024);            // 8 MB
    _Float16*  Apack    = (_Float16*)(ws + 128 * 1024 + 8 * MB);   // 8 MB
    _Float16*  Bpack    = (_Float16*)(ws + 128 * 1024 + 16 * MB);  // 8 MB
    _Float16*  logits   = (_Float16*)(ws + 128 * 1024 + 24 * MB);  // 32 MB (f16)

    pack_all<<<7168, 256, 0, stream>>>(x, w, pool, Apack, Bpack, poolh,
                                       colsum, failcnt);

    gemm256<<<16 * 16, 512, 0, stream>>>(Apack, Bpack, logits, 16);

    router_kernel<<<N_TOKENS, 256, 0, stream>>>(logits, Apack, poolh, out,
                                                minv, counts, failcnt, faillist);

    colsum_lg<<<dim3(NUM_SLOTS / 1024, N_TOKENS / 64), 256, 0, stream>>>(
        logits, minv, colsum);

    fixup_fin<<<64, 256, 0, stream>>>(logits, Apack, poolh, out, minv,
                                      counts, colsum, failcnt, faillist,
                                      out + (out_size - 2));
}

// Round 11
// 130.854 us; speedup vs baseline: 1.1476x; 1.1099x over previous
//
#include <hip/hip_runtime.h>
#include <math.h>
#include <stdint.h>

#define D_MODEL   1024
#define NUM_SLOTS 4096
#define N_TOKENS  4096   // 4 * 1024
#define MIN_K     8
#define MAX_K     32
#define KP        1024   // K elements
#define NSTEP     16     // KP / 64 (i8 MFMA consumes K=64)
#define CLIP_X    4.5f
#define CLIP_W    0.09f

typedef _Float16 f16x4 __attribute__((ext_vector_type(4)));
typedef _Float16 h2    __attribute__((ext_vector_type(2)));
typedef int      i32x4 __attribute__((ext_vector_type(4)));

__device__ __forceinline__ void gload16(const void* g, void* l) {
    __builtin_amdgcn_global_load_lds((const __attribute__((address_space(1))) void*)g,
                                     (__attribute__((address_space(3))) void*)l,
                                     16, 0, 0);
}

__device__ __forceinline__ h2 as_h2(uint32_t u) {
    union { uint32_t u; h2 h; } c; c.u = u; return c.h;
}
__device__ __forceinline__ uint32_t h2pack(float a, float b) {
    union { uint32_t u; h2 h; } c; c.h.x = (_Float16)a; c.h.y = (_Float16)b; return c.u;
}

// ordered-uint transform: u32 order == float order (all finite values)
__device__ __forceinline__ uint32_t ford(float f) {
    uint32_t b = __float_as_uint(f);
    return b ^ (uint32_t)(((int32_t)b >> 31) | 0x80000000);
}

// quantize 4 floats to packed i8 (symmetric, clamp +-127)
__device__ __forceinline__ uint32_t q4(float a, float b, float c, float d, float qs) {
    int ia = __float2int_rn(a * qs); ia = ia > 127 ? 127 : (ia < -127 ? -127 : ia);
    int ib = __float2int_rn(b * qs); ib = ib > 127 ? 127 : (ib < -127 ? -127 : ib);
    int ic = __float2int_rn(c * qs); ic = ic > 127 ? 127 : (ic < -127 ? -127 : ic);
    int id = __float2int_rn(d * qs); id = id > 127 ? 127 : (id < -127 ? -127 : id);
    return (uint32_t)(ia & 255) | ((uint32_t)(ib & 255) << 8) |
           ((uint32_t)(ic & 255) << 16) | ((uint32_t)(id & 255) << 24);
}

// ---------------------------------------------------------------------------
// pack_all: fused  (1) x f32 -> A i8 [4096][1024] + Axh f16 (router copy)
//                  (2) w f32 [1024][4096] -> B^T i8 [4096][1024]
//                  (3) pool f32 -> f16 packed pairs
//                  (4) clear colsum+counts+failcnt+done
// ---------------------------------------------------------------------------
__global__ __launch_bounds__(256) void pack_all(const float* __restrict__ x,
                                                const float* __restrict__ w,
                                                const float* __restrict__ pool,
                                                int8_t* __restrict__ A8,
                                                int8_t* __restrict__ BT8,
                                                _Float16* __restrict__ Axh,
                                                uint32_t* __restrict__ poolh,
                                                float* __restrict__ clr,
                                                int* __restrict__ failcnt) {
    __shared__ float tile[64][65];
    const int bid = blockIdx.x;
    const int tid = threadIdx.x;

    if (bid < 4096) {
        // ---- pack_x: 4 elems/thread -> i8 (gemm) + f16 (router) ----
        if (bid < 32) clr[bid * 256 + tid] = 0.f;   // colsum+counts clear
        if (bid == 32 && tid == 0) { failcnt[0] = 0; failcnt[1] = 0; }
        const int i = bid * 256 + tid;              // quad index, 1M total
        const float4 v = reinterpret_cast<const float4*>(x)[i];
        const int t = i >> 8;                       // 256 quads per 1024-row
        const int d = (i & 255) << 2;
        f16x4 hi;
        hi[0] = (_Float16)v.x; hi[1] = (_Float16)v.y;
        hi[2] = (_Float16)v.z; hi[3] = (_Float16)v.w;
        *(f16x4*)(Axh + (size_t)t * KP + d) = hi;
        *(uint32_t*)(A8 + (size_t)t * KP + d) =
            q4(v.x, v.y, v.z, v.w, 127.f / CLIP_X);
    } else if (bid < 5120) {
        // ---- pack_wt: 64x64 transpose tile -> i8 ----
        const int b2 = bid - 4096;
        const int n0 = (b2 & 63) * 64;
        const int k0 = (b2 >> 6) * 64;
        {
            const int c  = tid & 63;
            const int r0 = tid >> 6;       // 0..3
#pragma unroll
            for (int i = 0; i < 16; ++i) {
                const int r = r0 * 16 + i;
                tile[r][c] = w[(size_t)(k0 + r) * NUM_SLOTS + n0 + c];
            }
        }
        __syncthreads();
        const int nl  = tid >> 2;          // 0..63
        const int kl0 = (tid & 3) * 16;    // 0,16,32,48
        int8_t* rowp = BT8 + (size_t)(n0 + nl) * KP + k0;
#pragma unroll
        for (int j4 = 0; j4 < 16; j4 += 4) {
            const uint32_t u = q4(tile[kl0 + j4][nl], tile[kl0 + j4 + 1][nl],
                                  tile[kl0 + j4 + 2][nl], tile[kl0 + j4 + 3][nl],
                                  127.f / CLIP_W);
            *(uint32_t*)(rowp + kl0 + j4) = u;
        }
    } else {
        // ---- pack_pool: 8 elems/thread -> packed f16 pairs ----
        const size_t i = (size_t)(bid - 5120) * 256 + tid;
        const float4* s4 = reinterpret_cast<const float4*>(pool);
        const float4 a = s4[2 * i];
        const float4 b = s4[2 * i + 1];
        uint4 u;
        u.x = h2pack(a.x, a.y);
        u.y = h2pack(a.z, a.w);
        u.z = h2pack(b.x, b.y);
        u.w = h2pack(b.z, b.w);
        reinterpret_cast<uint4*>(poolh)[i] = u;
    }
}

// ---------------------------------------------------------------------------
// gemm256 (i8): 256x256 tile, 64B K-step rows, 8 waves, counted vmcnt, LDS
// slot-swizzle, setprio, XCD swizzle. Byte-geometry identical to the proven
// f16 kernel (64B rows, 4x16B swizzled slots); mfma_i32_16x16x64_i8.
// Logits dequantized to f16 in epilogue.
// ---------------------------------------------------------------------------
#define STAGE_A(NXT, S2) \
    gload16(gA0 + (size_t)(S2) * 64, (void*)(As8 + (NXT) * 16384 + tid * 16)); \
    gload16(gA1 + (size_t)(S2) * 64, (void*)(As8 + (NXT) * 16384 + 8192 + tid * 16));
#define STAGE_B(NXT, S2) \
    gload16(gB0 + (size_t)(S2) * 64, (void*)(Bs8 + (NXT) * 16384 + tid * 16)); \
    gload16(gB1 + (size_t)(S2) * 64, (void*)(Bs8 + (NXT) * 16384 + 8192 + tid * 16));

#define MM(AF, M) \
    acc[M][0] = __builtin_amdgcn_mfma_i32_16x16x64_i8(AF, bf0, acc[M][0], 0, 0, 0); \
    acc[M][1] = __builtin_amdgcn_mfma_i32_16x16x64_i8(AF, bf1, acc[M][1], 0, 0, 0); \
    acc[M][2] = __builtin_amdgcn_mfma_i32_16x16x64_i8(AF, bf2, acc[M][2], 0, 0, 0); \
    acc[M][3] = __builtin_amdgcn_mfma_i32_16x16x64_i8(AF, bf3, acc[M][3], 0, 0, 0);

#define GSTEP(S, CUR, NXT) do { \
    const int8_t* a_ = As8 + (CUR) * 16384; \
    const int8_t* b_ = Bs8 + (CUR) * 16384; \
    i32x4 bf0 = *(const i32x4*)(b_ + offB0); \
    i32x4 bf1 = *(const i32x4*)(b_ + offB1); \
    i32x4 bf2 = *(const i32x4*)(b_ + offB2); \
    i32x4 bf3 = *(const i32x4*)(b_ + offB3); \
    i32x4 a0 = *(const i32x4*)(a_ + offA0); \
    i32x4 a1 = *(const i32x4*)(a_ + offA1); \
    i32x4 a2 = *(const i32x4*)(a_ + offA2); \
    i32x4 a3 = *(const i32x4*)(a_ + offA3); \
    if ((S) + 2 < NSTEP) { STAGE_A(NXT, (S) + 2) } \
    asm volatile("" ::: "memory"); \
    __builtin_amdgcn_s_barrier(); \
    __builtin_amdgcn_s_setprio(1); \
    MM(a0, 0) MM(a1, 1) MM(a2, 2) MM(a3, 3) \
    __builtin_amdgcn_s_setprio(0); \
    asm volatile("" ::: "memory"); \
    __builtin_amdgcn_s_barrier(); \
    a0 = *(const i32x4*)(a_ + offA4); \
    a1 = *(const i32x4*)(a_ + offA5); \
    a2 = *(const i32x4*)(a_ + offA6); \
    a3 = *(const i32x4*)(a_ + offA7); \
    if ((S) + 2 < NSTEP) { STAGE_B(NXT, (S) + 2) } \
    asm volatile("" ::: "memory"); \
    __builtin_amdgcn_s_barrier(); \
    __builtin_amdgcn_s_setprio(1); \
    MM(a0, 4) MM(a1, 5) MM(a2, 6) MM(a3, 7) \
    __builtin_amdgcn_s_setprio(0); \
    if ((S) < NSTEP - 2) { asm volatile("s_waitcnt vmcnt(4)" ::: "memory"); } \
    else                 { asm volatile("s_waitcnt vmcnt(0)" ::: "memory"); } \
    __builtin_amdgcn_s_barrier(); \
} while (0)

__global__ __launch_bounds__(512, 2) void gemm256(const int8_t* __restrict__ A,
                                                  const int8_t* __restrict__ BT,
                                                  _Float16* __restrict__ C,
                                                  int nbm) {
    __shared__ int8_t As8[4 * 16384] __attribute__((aligned(16)));  // 64KB
    __shared__ int8_t Bs8[4 * 16384] __attribute__((aligned(16)));  // 64KB
    const int tid  = threadIdx.x;
    const int lane = tid & 63;
    const int wv   = tid >> 6;           // 0..7
    const int wm   = wv >> 2;            // 0..1
    const int wn   = wv & 3;             // 0..3

    // ---- XCD-aware decode: grid 16x16 -> each XCD owns a 4x8 region ----
    int brow, bcol;
    {
        const int bid = blockIdx.x;
        if (nbm == 16) {
            const int xcd = bid & 7;
            const int l   = bid >> 3;          // 0..31
            brow = (xcd & 3) * 4 + (l & 3);
            bcol = (xcd >> 2) * 8 + (l >> 2);
        } else {
            brow = bid >> 4;
            bcol = bid & 15;
        }
    }
    const size_t bm = (size_t)brow * 256;
    const size_t bn = (size_t)bcol * 256;

    const int rowA = tid >> 2;               // 0..127 (row within half)
    const int slot = tid & 3;                // 16B slot within 64B row
    const int sswz = slot ^ ((rowA >> 1) & 3);
    const int8_t* gA0 = A  + (bm + rowA) * (size_t)KP + sswz * 16;
    const int8_t* gA1 = A  + (bm + rowA + 128) * (size_t)KP + sswz * 16;
    const int8_t* gB0 = BT + (bn + rowA) * (size_t)KP + sswz * 16;
    const int8_t* gB1 = BT + (bn + rowA + 128) * (size_t)KP + sswz * 16;

    int offA0, offA1, offA2, offA3, offA4, offA5, offA6, offA7;
    int offB0, offB1, offB2, offB3;
    {
        const int r15 = lane & 15, ls = lane >> 4;
#define AOFF(M) (((wm) * 128 + (M) * 16 + r15) * 64 + \
                 ((ls ^ ((((wm) * 128 + (M) * 16 + r15) >> 1) & 3)) * 16))
#define BOFF(N) (((wn) * 64 + (N) * 16 + r15) * 64 + \
                 ((ls ^ ((((wn) * 64 + (N) * 16 + r15) >> 1) & 3)) * 16))
        offA0 = AOFF(0); offA1 = AOFF(1); offA2 = AOFF(2); offA3 = AOFF(3);
        offA4 = AOFF(4); offA5 = AOFF(5); offA6 = AOFF(6); offA7 = AOFF(7);
        offB0 = BOFF(0); offB1 = BOFF(1); offB2 = BOFF(2); offB3 = BOFF(3);
#undef AOFF
#undef BOFF
    }

    i32x4 acc[8][4] = {};

    STAGE_A(0, 0) STAGE_B(0, 0)
    STAGE_A(1, 1) STAGE_B(1, 1)
    asm volatile("s_waitcnt vmcnt(4)" ::: "memory");
    __builtin_amdgcn_s_barrier();

    for (int s4 = 0; s4 < NSTEP; s4 += 4) {
        GSTEP(s4 + 0, 0, 2);
        GSTEP(s4 + 1, 1, 3);
        GSTEP(s4 + 2, 2, 0);
        GSTEP(s4 + 3, 3, 1);
    }

    const float sc = (CLIP_X / 127.f) * (CLIP_W / 127.f);
    const size_t crow = bm + wm * 128 + ((lane >> 4) << 2);
    const size_t ccol = bn + wn * 64 + (lane & 15);
#pragma unroll
    for (int m = 0; m < 8; ++m)
#pragma unroll
        for (int r = 0; r < 4; ++r) {
            _Float16* cp = C + (crow + m * 16 + r) * (size_t)NUM_SLOTS + ccol;
#pragma unroll
            for (int n = 0; n < 4; ++n)
                cp[n * 16] = (_Float16)((float)acc[m][n][r] * sc);
        }
}

// ---------------------------------------------------------------------------
// router v11 (byte-identical to R10): fast path + tie-tolerant validity +
// setprio on serial region; f16 logits; f16 x from Axh; f16 pool.
// ---------------------------------------------------------------------------
#define RECOMP(G, A, B, Cc, D) do { \
    uint32_t t0 = (msk & (1u << (A)))  ? k##A  : 0u; \
    uint32_t t1 = (msk & (1u << (B)))  ? k##B  : 0u; \
    uint32_t t2 = (msk & (1u << (Cc))) ? k##Cc : 0u; \
    uint32_t t3 = (msk & (1u << (D)))  ? k##D  : 0u; \
    t0 = t0 > t1 ? t0 : t1; t2 = t2 > t3 ? t2 : t3; \
    gm##G = t0 > t2 ? t0 : t2; } while (0)

#define XROUND(IT) do { \
    uint32_t best = gm0; \
    if (gm1 > best) best = gm1; \
    if (gm2 > best) best = gm2; \
    if (gm3 > best) best = gm3; \
    uint32_t wb = best; \
    _Pragma("unroll") \
    for (int o = 32; o; o >>= 1) { \
        const uint32_t p = __shfl_xor(wb, o); \
        if (p > wb) wb = p; \
    } \
    if (lane == (IT)) kept = wb; \
    if (best == wb) { \
        const int idx = 4095 - (int)(wb & 0xFFFu); \
        const int rem = idx - kb; \
        const int jj = rem >> 8; \
        msk &= ~(1u << (4 * jj + (rem & 3))); \
        switch (jj) { \
            case 0:  RECOMP(0, 0, 1, 2, 3); break; \
            case 1:  RECOMP(1, 4, 5, 6, 7); break; \
            case 2:  RECOMP(2, 8, 9, 10, 11); break; \
            default: RECOMP(3, 12, 13, 14, 15); break; \
        } \
    } \
} while (0)

// load f16 logit quad groups with the SAME slot mapping as the f32 version
#define LOADLV(TOK) \
    const uint2* lrow2 = reinterpret_cast<const uint2*>(logits + (size_t)(TOK) * NUM_SLOTS + wseg); \
    float4 lv0, lv1, lv2, lv3; \
    { \
        const uint2 u0 = lrow2[lane]; \
        const uint2 u1 = lrow2[lane + 64]; \
        const uint2 u2 = lrow2[lane + 128]; \
        const uint2 u3 = lrow2[lane + 192]; \
        h2 ha, hb; \
        ha = as_h2(u0.x); hb = as_h2(u0.y); \
        lv0 = make_float4((float)ha.x, (float)ha.y, (float)hb.x, (float)hb.y); \
        ha = as_h2(u1.x); hb = as_h2(u1.y); \
        lv1 = make_float4((float)ha.x, (float)ha.y, (float)hb.x, (float)hb.y); \
        ha = as_h2(u2.x); hb = as_h2(u2.y); \
        lv2 = make_float4((float)ha.x, (float)ha.y, (float)hb.x, (float)hb.y); \
        ha = as_h2(u3.x); hb = as_h2(u3.y); \
        lv3 = make_float4((float)ha.x, (float)ha.y, (float)hb.x, (float)hb.y); \
    }

#define MAKEKEYS(E0, E1, E2, E3) \
    k0  = (ford((E0).x) & 0xFFFFF000u) | (uint32_t)(4095 - (kb + 0)); \
    k1  = (ford((E0).y) & 0xFFFFF000u) | (uint32_t)(4095 - (kb + 1)); \
    k2  = (ford((E0).z) & 0xFFFFF000u) | (uint32_t)(4095 - (kb + 2)); \
    k3  = (ford((E0).w) & 0xFFFFF000u) | (uint32_t)(4095 - (kb + 3)); \
    k4  = (ford((E1).x) & 0xFFFFF000u) | (uint32_t)(4095 - (kb + 256)); \
    k5  = (ford((E1).y) & 0xFFFFF000u) | (uint32_t)(4095 - (kb + 257)); \
    k6  = (ford((E1).z) & 0xFFFFF000u) | (uint32_t)(4095 - (kb + 258)); \
    k7  = (ford((E1).w) & 0xFFFFF000u) | (uint32_t)(4095 - (kb + 259)); \
    k8  = (ford((E2).x) & 0xFFFFF000u) | (uint32_t)(4095 - (kb + 512)); \
    k9  = (ford((E2).y) & 0xFFFFF000u) | (uint32_t)(4095 - (kb + 513)); \
    k10 = (ford((E2).z) & 0xFFFFF000u) | (uint32_t)(4095 - (kb + 514)); \
    k11 = (ford((E2).w) & 0xFFFFF000u) | (uint32_t)(4095 - (kb + 515)); \
    k12 = (ford((E3).x) & 0xFFFFF000u) | (uint32_t)(4095 - (kb + 768)); \
    k13 = (ford((E3).y) & 0xFFFFF000u) | (uint32_t)(4095 - (kb + 769)); \
    k14 = (ford((E3).z) & 0xFFFFF000u) | (uint32_t)(4095 - (kb + 770)); \
    k15 = (ford((E3).w) & 0xFFFFF000u) | (uint32_t)(4095 - (kb + 771));

// fused proj + cross-wave out merge (f16 pool + f16 x from Axh)
#define PROJ_AND_OUT(TOK) do { \
    const uint4* xA = reinterpret_cast<const uint4*>(Af + (size_t)(TOK) * D_MODEL); \
    const uint4 xq0 = xA[lane]; \
    const uint4 xq1 = xA[lane + 64]; \
    const h2 xh0 = as_h2(xq0.x), xh1 = as_h2(xq0.y); \
    const h2 xh2 = as_h2(xq0.z), xh3 = as_h2(xq0.w); \
    const h2 xh4 = as_h2(xq1.x), xh5 = as_h2(xq1.y); \
    const h2 xh6 = as_h2(xq1.z), xh7 = as_h2(xq1.w); \
    float4 oa0 = {0,0,0,0}, ob0 = {0,0,0,0}, oa1 = {0,0,0,0}, ob1 = {0,0,0,0}; \
    _Pragma("unroll") \
    for (int ii = 0; ii < 8; ++ii) { \
        const int   i     = w * 8 + ii; \
        const int   slotg = __shfl(slotv, i); \
        const float wgt   = __shfl(wgtl, i); \
        if (wgt != 0.f) { \
            const uint4* pr = reinterpret_cast<const uint4*>(poolh + (size_t)slotg * (D_MODEL / 2)); \
            const uint4 q0 = pr[lane]; \
            const uint4 q1 = pr[lane + 64]; \
            const h2 p0 = as_h2(q0.x), p1 = as_h2(q0.y); \
            const h2 p2 = as_h2(q0.z), p3 = as_h2(q0.w); \
            const h2 p4 = as_h2(q1.x), p5 = as_h2(q1.y); \
            const h2 p6 = as_h2(q1.z), p7 = as_h2(q1.w); \
            h2 acc2 = xh0 * p0; \
            acc2 = xh1 * p1 + acc2; \
            acc2 = xh2 * p2 + acc2; \
            acc2 = xh3 * p3 + acc2; \
            acc2 = xh4 * p4 + acc2; \
            acc2 = xh5 * p5 + acc2; \
            acc2 = xh6 * p6 + acc2; \
            acc2 = xh7 * p7 + acc2; \
            float d = (float)acc2.x + (float)acc2.y; \
            _Pragma("unroll") \
            for (int o = 32; o; o >>= 1) d += __shfl_xor(d, o); \
            const float wp = d * wgt; \
            oa0.x = fmaf(wp, (float)p0.x, oa0.x); oa0.y = fmaf(wp, (float)p0.y, oa0.y); \
            oa0.z = fmaf(wp, (float)p1.x, oa0.z); oa0.w = fmaf(wp, (float)p1.y, oa0.w); \
            ob0.x = fmaf(wp, (float)p2.x, ob0.x); ob0.y = fmaf(wp, (float)p2.y, ob0.y); \
            ob0.z = fmaf(wp, (float)p3.x, ob0.z); ob0.w = fmaf(wp, (float)p3.y, ob0.w); \
            oa1.x = fmaf(wp, (float)p4.x, oa1.x); oa1.y = fmaf(wp, (float)p4.y, oa1.y); \
            oa1.z = fmaf(wp, (float)p5.x, oa1.z); oa1.w = fmaf(wp, (float)p5.y, oa1.w); \
            ob1.x = fmaf(wp, (float)p6.x, ob1.x); ob1.y = fmaf(wp, (float)p6.y, ob1.y); \
            ob1.z = fmaf(wp, (float)p7.x, ob1.z); ob1.w = fmaf(wp, (float)p7.y, ob1.w); \
        } \
    } \
    { \
        float4* op = reinterpret_cast<float4*>(s_union + w * 1024); \
        op[2 * lane]       = oa0; \
        op[2 * lane + 1]   = ob0; \
        op[2 * lane + 128] = oa1; \
        op[2 * lane + 129] = ob1; \
    } \
    __syncthreads(); \
    float4 r = {0, 0, 0, 0}; \
    _Pragma("unroll") \
    for (int ww = 0; ww < 4; ++ww) { \
        const float4 vv = reinterpret_cast<const float4*>(s_union + ww * 1024)[tid]; \
        r.x += vv.x; r.y += vv.y; r.z += vv.z; r.w += vv.w; \
    } \
    reinterpret_cast<float4*>(out + (size_t)(TOK) * D_MODEL)[tid] = r; \
} while (0)

__global__ __launch_bounds__(256) void router_kernel(
    const _Float16* __restrict__ logits,     // [4096][4096] f16
    const _Float16* __restrict__ Af,         // Axh: x as f16 [4096][1024]
    const uint32_t* __restrict__ poolh,      // [4096][512] packed f16 pairs
    float* __restrict__ out,                 // [4096][1024]
    float2* __restrict__ minv,               // [4096] (m, inv) per token
    float* __restrict__ counts,
    int* __restrict__ failcnt,
    int* __restrict__ faillist) {
    __shared__ float    s_union[NUM_SLOTS];  // logit table, then out-partials
    __shared__ uint32_t s_cand[68];          // [0..63] candidates, [64..67] rmax
    __shared__ float    s_redv[4];

    const int tid  = threadIdx.x;
    const int w    = tid >> 6;
    const int lane = tid & 63;
    const int wseg = w << 10;
    const int t    = blockIdx.x;

    LOADLV(t)

    reinterpret_cast<float4*>(s_union + wseg)[lane]       = lv0;
    reinterpret_cast<float4*>(s_union + wseg)[lane + 64]  = lv1;
    reinterpret_cast<float4*>(s_union + wseg)[lane + 128] = lv2;
    reinterpret_cast<float4*>(s_union + wseg)[lane + 192] = lv3;

    __builtin_amdgcn_s_setprio(1);

    float lmax = fmaxf(fmaxf(fmaxf(lv0.x, lv0.y), fmaxf(lv0.z, lv0.w)),
                       fmaxf(fmaxf(lv1.x, lv1.y), fmaxf(lv1.z, lv1.w)));
    lmax = fmaxf(lmax, fmaxf(fmaxf(lv2.x, lv2.y), fmaxf(lv2.z, lv2.w)));
    lmax = fmaxf(lmax, fmaxf(fmaxf(lv3.x, lv3.y), fmaxf(lv3.z, lv3.w)));
#pragma unroll
    for (int o = 32; o; o >>= 1) lmax = fmaxf(lmax, __shfl_xor(lmax, o));
    if (lane == 0) s_redv[w] = lmax;
    __syncthreads();
    const float m = fmaxf(fmaxf(s_redv[0], s_redv[1]), fmaxf(s_redv[2], s_redv[3]));
    __syncthreads();

    // ---- e = exp(l - m); denom ----
    float lsum;
    {
        float4 ev0, ev1, ev2, ev3;
        ev0.x = __expf(lv0.x - m); ev0.y = __expf(lv0.y - m);
        ev0.z = __expf(lv0.z - m); ev0.w = __expf(lv0.w - m);
        ev1.x = __expf(lv1.x - m); ev1.y = __expf(lv1.y - m);
        ev1.z = __expf(lv1.z - m); ev1.w = __expf(lv1.w - m);
        ev2.x = __expf(lv2.x - m); ev2.y = __expf(lv2.y - m);
        ev2.z = __expf(lv2.z - m); ev2.w = __expf(lv2.w - m);
        ev3.x = __expf(lv3.x - m); ev3.y = __expf(lv3.y - m);
        ev3.z = __expf(lv3.z - m); ev3.w = __expf(lv3.w - m);
        lsum = (ev0.x + ev0.y + ev0.z + ev0.w) + (ev1.x + ev1.y + ev1.z + ev1.w) +
               (ev2.x + ev2.y + ev2.z + ev2.w) + (ev3.x + ev3.y + ev3.z + ev3.w);
    }
#pragma unroll
    for (int o = 32; o; o >>= 1) lsum += __shfl_xor(lsum, o);
    if (lane == 0) s_redv[w] = lsum;
    __syncthreads();
    const float inv = 1.0f / (s_redv[0] + s_redv[1] + s_redv[2] + s_redv[3]);
    if (tid == 0) minv[t] = make_float2(m, inv);

    // ---- named u32 keys ----
    const int kb = wseg + 4 * lane;
    uint32_t k0, k1, k2, k3, k4, k5, k6, k7;
    uint32_t k8, k9, k10, k11, k12, k13, k14, k15;
    MAKEKEYS(lv0, lv1, lv2, lv3)

    uint32_t msk = 0xFFFFu;
    uint32_t gm0, gm1, gm2, gm3;
    RECOMP(0, 0, 1, 2, 3); RECOMP(1, 4, 5, 6, 7);
    RECOMP(2, 8, 9, 10, 11); RECOMP(3, 12, 13, 14, 15);

    // ---- fast path: 16 extraction rounds per wave ----
    uint32_t kept = 0;
    for (int it = 0; it < 16; ++it) { XROUND(it); }

    // wave's largest remaining key -> s_cand[64+w]
    {
        uint32_t best = gm0;
        if (gm1 > best) best = gm1;
        if (gm2 > best) best = gm2;
        if (gm3 > best) best = gm3;
#pragma unroll
        for (int o = 32; o; o >>= 1) {
            const uint32_t p = __shfl_xor(best, o);
            if (p > best) best = p;
        }
        if (lane == 0) s_cand[64 + w] = best;
    }
    if (lane < 16) s_cand[w * 16 + lane] = kept;
    __syncthreads();

    // ---- 64-wide bitonic descending sort of the 4x16 candidates ----
    uint32_t v0 = s_cand[lane];
#pragma unroll
    for (int k = 2; k <= 64; k <<= 1) {
#pragma unroll
        for (int j = k >> 1; j > 0; j >>= 1) {
            const bool jl = (lane & j) == 0;
            const uint32_t p = __shfl_xor(v0, j);
            const bool km = ((lane & k) == 0) == jl;
            v0 = ((p > v0) == km) ? p : v0;
        }
    }

    // ---- validity (tie-tolerant): fail only if a remaining key's VALUE
    //      strictly beats the 32nd candidate's VALUE ----
    const uint32_t th = __shfl(v0, 31);
    uint32_t mw = s_cand[64];
    {
        const uint32_t m1 = s_cand[65], m2 = s_cand[66], m3 = s_cand[67];
        if (m1 > mw) mw = m1;
        if (m2 > mw) mw = m2;
        if (m3 > mw) mw = m3;
    }
    if ((mw & 0xFFFFF000u) > (th & 0xFFFFF000u)) {   // block-uniform; rare
        __builtin_amdgcn_s_setprio(0);
        if (tid == 0) {
            const int fi = atomicAdd(failcnt, 1);
            faillist[fi] = t;
        }
        return;                          // fixup kernel handles this token
    }

    // ---- ranks 0..31 in v0 lanes 0..31; recover p from LDS logit table ----
    const int slotv = 4095 - (int)(v0 & 0xFFFu);
    float pv = 0.f;
    if (lane < 32) pv = __expf(s_union[slotv] - m) * inv;
    const bool kp = (lane < MIN_K) || (pv > (1.0f / 4096.0f));  // lanes>=32: false
    float wsum = kp ? pv : 0.f;
#pragma unroll
    for (int o = 32; o; o >>= 1) wsum += __shfl_xor(wsum, o);
    const float wgtl = kp ? pv / (wsum + 1e-9f) : 0.f;
    if (w == 0 && lane < 32 && kp) atomicAdd(&counts[slotv], 1.0f);

    __builtin_amdgcn_s_setprio(0);   // memory-heavy proj runs at normal prio
    __syncthreads();   // all s_union (logit) reads done before reuse

    PROJ_AND_OUT(t);
}

// ---------------------------------------------------------------------------
// colsum_lg: colsum[n] = sum_t exp(logit[t][n] - m_t) * inv_t  (f16 logits)
// ---------------------------------------------------------------------------
__global__ __launch_bounds__(256) void colsum_lg(const _Float16* __restrict__ logits,
                                                 const float2* __restrict__ minv,
                                                 float* __restrict__ colsum) {
    const int tid = threadIdx.x;
    const int s0  = blockIdx.x * 1024;
    const int t0  = blockIdx.y * 64;
    float a0 = 0.f, a1 = 0.f, a2 = 0.f, a3 = 0.f;
    for (int t = 0; t < 64; ++t) {
        const float2 mv = minv[t0 + t];
        const uint2 v = reinterpret_cast<const uint2*>(
            logits + (size_t)(t0 + t) * NUM_SLOTS + s0)[tid];
        const h2 va = as_h2(v.x), vb = as_h2(v.y);
        a0 = fmaf(__expf((float)va.x - mv.x), mv.y, a0);
        a1 = fmaf(__expf((float)va.y - mv.x), mv.y, a1);
        a2 = fmaf(__expf((float)vb.x - mv.x), mv.y, a2);
        a3 = fmaf(__expf((float)vb.y - mv.x), mv.y, a3);
    }
    const int c = s0 + 4 * tid;
    atomicAdd(&colsum[c + 0], a0);
    atomicAdd(&colsum[c + 1], a1);
    atomicAdd(&colsum[c + 2], a2);
    atomicAdd(&colsum[c + 3], a3);
}

// ---------------------------------------------------------------------------
// fixup_fin: exact full path for failed tokens + last-block finalize.
// ---------------------------------------------------------------------------
__global__ __launch_bounds__(256) void fixup_fin(
    const _Float16* __restrict__ logits,
    const _Float16* __restrict__ Af,
    const uint32_t* __restrict__ poolh,
    float* __restrict__ out,
    const float2* __restrict__ minv,
    float* __restrict__ counts,
    float* __restrict__ colsum,
    int* __restrict__ failcnt,
    const int* __restrict__ faillist,
    float* __restrict__ out2) {
    __shared__ float    s_union[NUM_SLOTS];
    __shared__ uint32_t s_cand[128];
    __shared__ float    s_tot[4], s_act[4], s_dot[4];
    __shared__ int      s_last;

    const int tid  = threadIdx.x;
    const int w    = tid >> 6;
    const int lane = tid & 63;
    const int wseg = w << 10;
    const int n    = failcnt[0];

    for (int fi = blockIdx.x; fi < n; fi += gridDim.x) {
        const int t = faillist[fi];
        LOADLV(t)
        reinterpret_cast<float4*>(s_union + wseg)[lane]       = lv0;
        reinterpret_cast<float4*>(s_union + wseg)[lane + 64]  = lv1;
        reinterpret_cast<float4*>(s_union + wseg)[lane + 128] = lv2;
        reinterpret_cast<float4*>(s_union + wseg)[lane + 192] = lv3;
        const float2 mv = minv[t];
        const float m = mv.x, inv = mv.y;

        const int kb = wseg + 4 * lane;
        uint32_t k0, k1, k2, k3, k4, k5, k6, k7;
        uint32_t k8, k9, k10, k11, k12, k13, k14, k15;
        MAKEKEYS(lv0, lv1, lv2, lv3)

        uint32_t msk = 0xFFFFu;
        uint32_t gm0, gm1, gm2, gm3;
        RECOMP(0, 0, 1, 2, 3); RECOMP(1, 4, 5, 6, 7);
        RECOMP(2, 8, 9, 10, 11); RECOMP(3, 12, 13, 14, 15);

        uint32_t kept = 0;
        for (int it = 0; it < 32; ++it) { XROUND(it); }
        if (lane < 32) s_cand[w * 32 + lane] = kept;
        __syncthreads();

        uint32_t v0 = s_cand[lane];
        uint32_t v1 = s_cand[64 + lane];
#pragma unroll
        for (int k = 2; k <= 128; k <<= 1) {
#pragma unroll
            for (int j = k >> 1; j > 0; j >>= 1) {
                if (j == 64) {
                    const uint32_t a = v0 > v1 ? v0 : v1;
                    const uint32_t b = v0 > v1 ? v1 : v0;
                    v0 = a; v1 = b;
                } else {
                    const bool jl = (lane & j) == 0;
                    {
                        const uint32_t p = __shfl_xor(v0, j);
                        const bool km = ((lane & k) == 0) == jl;
                        v0 = ((p > v0) == km) ? p : v0;
                    }
                    {
                        const uint32_t p = __shfl_xor(v1, j);
                        const bool km = (((lane + 64) & k) == 0) == jl;
                        v1 = ((p > v1) == km) ? p : v1;
                    }
                }
            }
        }

        const int slotv = 4095 - (int)(v0 & 0xFFFu);
        float pv = 0.f;
        if (lane < 32) pv = __expf(s_union[slotv] - m) * inv;
        const bool kp = (lane < MIN_K) || (pv > (1.0f / 4096.0f));
        float wsum = kp ? pv : 0.f;
#pragma unroll
        for (int o = 32; o; o >>= 1) wsum += __shfl_xor(wsum, o);
        const float wgtl = kp ? pv / (wsum + 1e-9f) : 0.f;
        if (w == 0 && lane < 32 && kp) atomicAdd(&counts[slotv], 1.0f);
        __syncthreads();

        PROJ_AND_OUT(t);
        __syncthreads();   // s_union reuse across fail-list iterations
    }

    // ---- completion + last-block finalize (R6-proven coherence pattern) ----
    __threadfence();
    __syncthreads();
    if (tid == 0) s_last = (atomicAdd(&failcnt[1], 1) == (int)gridDim.x - 1) ? 1 : 0;
    __syncthreads();
    if (s_last) {
        __threadfence();
        float tot = 0.f, act = 0.f, dot = 0.f;
#pragma unroll
        for (int j = 0; j < 16; ++j) {
            const int i = j * 256 + tid;
            const float c  = atomicAdd(&counts[i], 0.f);  // device-coherent read
            const float cs = colsum[i];                   // prior-kernel data
            tot += c;
            act += (c > 0.f) ? 1.f : 0.f;
            dot += cs * c;
        }
#pragma unroll
        for (int o = 32; o; o >>= 1) {
            tot += __shfl_xor(tot, o);
            act += __shfl_xor(act, o);
            dot += __shfl_xor(dot, o);
        }
        if ((tid & 63) == 0) {
            s_tot[tid >> 6] = tot; s_act[tid >> 6] = act; s_dot[tid >> 6] = dot;
        }
        __syncthreads();
        if (tid == 0) {
            const float T  = s_tot[0] + s_tot[1] + s_tot[2] + s_tot[3];
            const float A  = s_act[0] + s_act[1] + s_act[2] + s_act[3];
            const float Dt = s_dot[0] + s_dot[1] + s_dot[2] + s_dot[3];
            out2[0] = Dt / (T + 1e-9f);   // (4096 tokens) x (N=4096) cancel
            out2[1] = A;
        }
    }
}

// ---------------------------------------------------------------------------
extern "C" void kernel_launch(void* const* d_in, const int* in_sizes, int n_in,
                              void* d_out, int out_size, void* d_ws, size_t ws_size,
                              hipStream_t stream) {
    const float* x    = (const float*)d_in[0];
    const float* pool = (const float*)d_in[1];
    const float* w    = (const float*)d_in[2];
    float* out = (float*)d_out;

    // workspace layout (~56.1 MB total)
    const size_t MB = 1024 * 1024;
    char* ws = (char*)d_ws;
    float*     colsum   = (float*)ws;                              // 16 KB
    float*     counts   = (float*)(ws + 16 * 1024);                // 16 KB
    float2*    minv     = (float2*)(ws + 32 * 1024);               // 32 KB
    int*       failcnt  = (int*)(ws + 64 * 1024);                  // [0]=cnt [1]=done
    int*       faillist = (int*)(ws + 68 * 1024);                  // 16 KB
    uint32_t*  poolh    = (uint32_t*)(ws + 128 * 1024);            // 8 MB
    int8_t*    A8       = (int8_t*)(ws + 128 * 1024 + 8 * MB);     // 4 MB
    int8_t*    B8       = (int8_t*)(ws + 128 * 1024 + 12 * MB);    // 4 MB
    _Float16*  Axh      = (_Float16*)(ws + 128 * 1024 + 16 * MB);  // 8 MB
    _Float16*  logits   = (_Float16*)(ws + 128 * 1024 + 24 * MB);  // 32 MB (f16)

    pack_all<<<7168, 256, 0, stream>>>(x, w, pool, A8, B8, Axh, poolh,
                                       colsum, failcnt);

    gemm256<<<16 * 16, 512, 0, stream>>>(A8, B8, logits, 16);

    router_kernel<<<N_TOKENS, 256, 0, stream>>>(logits, Axh, poolh, out,
                                                minv, counts, failcnt, faillist);

    colsum_lg<<<dim3(NUM_SLOTS / 1024, N_TOKENS / 64), 256, 0, stream>>>(
        logits, minv, colsum);

    fixup_fin<<<64, 256, 0, stream>>>(logits, Axh, poolh, out, minv,
                                      counts, colsum, failcnt, faillist,
                                      out + (out_size - 2));
}